// Round 1
// baseline (1614.113 us; speedup 1.0000x reference)
//
#include <hip/hip_runtime.h>

// Problem constants
constexpr int Bn = 32, Ln = 300, Dn = 256;
constexpr int Nn = Bn * Ln;          // 9600
constexpr int En = 4000, NNZn = 100000;
constexpr int DUn = 128, DFn = 384;
constexpr long NDl = (long)Nn * Dn;  // 2457600

// ---------------- utility kernels ----------------
__global__ void zero_kernel(float* __restrict__ p, int n) {
    int i = blockIdx.x * blockDim.x + threadIdx.x;
    if (i < n) p[i] = 0.f;
}

__global__ void count_deg(const int* __restrict__ node_idx, const int* __restrict__ edge_idx,
                          float* __restrict__ cnt_n, float* __restrict__ cnt_e, int nnz) {
    int k = blockIdx.x * blockDim.x + threadIdx.x;
    if (k < nnz) {
        atomicAdd(&cnt_e[edge_idx[k]], 1.f);
        atomicAdd(&cnt_n[node_idx[k]], 1.f);
    }
}

__global__ void recip_kernel(float* __restrict__ p, int n) {
    int i = blockIdx.x * blockDim.x + threadIdx.x;
    if (i < n) p[i] = 1.f / fmaxf(p[i], 1.f);
}

// ---------------- 64x64 register-blocked GEMM ----------------
// C[M,Nc] = A[M,K] @ B[K,Nc]  (A optionally gathered by rel)
// flags bit0: add bias[col]; bit1: add 0.002*PE(row%L, col)
template <bool GATHER>
__global__ void gemm64(const float* __restrict__ A, const int* __restrict__ rel,
                       const float* __restrict__ Bw, const float* __restrict__ bias,
                       float* __restrict__ C, int M, int K, int Nc, int flags) {
    __shared__ float As[16][65];  // As[k][m]
    __shared__ float Bs[16][68];  // Bs[k][n]  (row stride 68 keeps float4 alignment)
    const int tx = threadIdx.x, ty = threadIdx.y;
    const int tid = ty * 16 + tx;
    const int m0 = blockIdx.y * 64, n0 = blockIdx.x * 64;

    // A-tile load mapping: 64 rows x 16 k, float4 along k
    const int am = tid >> 2;            // 0..63
    const int ak = (tid & 3) * 4;       // 0,4,8,12
    long arow = m0 + am;
    if (GATHER) arow = rel[arow];
    const float* aptr = A + (size_t)arow * K + ak;
    // B-tile load mapping: 16 k x 64 n, float4 along n
    const int bk = tid >> 4;            // 0..15
    const int bn = (tid & 15) * 4;      // 0..60
    const float* bptr = Bw + (size_t)bk * Nc + n0 + bn;

    float acc[4][4] = {};
    for (int k0 = 0; k0 < K; k0 += 16) {
        float4 av = *(const float4*)(aptr + k0);
        float4 bv = *(const float4*)(bptr + (size_t)k0 * Nc);
        As[ak + 0][am] = av.x;
        As[ak + 1][am] = av.y;
        As[ak + 2][am] = av.z;
        As[ak + 3][am] = av.w;
        *(float4*)&Bs[bk][bn] = bv;
        __syncthreads();
#pragma unroll
        for (int kk = 0; kk < 16; kk++) {
            float a[4], b[4];
#pragma unroll
            for (int i = 0; i < 4; i++) a[i] = As[kk][ty * 4 + i];
#pragma unroll
            for (int j = 0; j < 4; j++) b[j] = Bs[kk][tx * 4 + j];
#pragma unroll
            for (int i = 0; i < 4; i++)
#pragma unroll
                for (int j = 0; j < 4; j++) acc[i][j] += a[i] * b[j];
        }
        __syncthreads();
    }
#pragma unroll
    for (int i = 0; i < 4; i++) {
        int row = m0 + ty * 4 + i;
#pragma unroll
        for (int j = 0; j < 4; j++) {
            int col = n0 + tx * 4 + j;
            float v = acc[i][j];
            if (flags & 1) v += bias[col];
            if (flags & 2) {
                int l = row % Ln;
                if (l > 0) {
                    int j2 = col >> 1;
                    float div = expf(-0.07195578415606394f * (float)j2);
                    float ang = (float)(l - 1) * div;
                    v += 0.002f * ((col & 1) ? cosf(ang) : sinf(ang));
                }
            }
            C[(size_t)row * Nc + col] = v;
        }
    }
}

// ---------------- hypergraph scatter kernels ----------------
__global__ void scatter_edge(const float* __restrict__ y, const int* __restrict__ node_idx,
                             const int* __restrict__ edge_idx, float* __restrict__ e) {
    int k = blockIdx.x;
    int d = threadIdx.x;
    int n = node_idx[k], ed = edge_idx[k];
    atomicAdd(&e[(size_t)ed * Dn + d], y[(size_t)n * Dn + d]);
}

__global__ void scatter_node(const float* __restrict__ e, const float* __restrict__ invE,
                             const int* __restrict__ node_idx, const int* __restrict__ edge_idx,
                             float* __restrict__ o) {
    int k = blockIdx.x;
    int d = threadIdx.x;
    int n = node_idx[k], ed = edge_idx[k];
    atomicAdd(&o[(size_t)n * Dn + d], e[(size_t)ed * Dn + d] * invE[ed]);
}

__global__ void finalize_node(float* __restrict__ o, const float* __restrict__ invN,
                              const float* __restrict__ bias, int n) {
    int i = blockIdx.x * blockDim.x + threadIdx.x;
    if (i < n) {
        int node = i >> 8;  // Dn = 256
        int d = i & 255;
        o[i] = o[i] * invN[node] + bias[d];
    }
}

// ---------------- tail kernels ----------------
__global__ void build_user(const float* __restrict__ tg, const float* __restrict__ ig,
                           const float* __restrict__ ut, const int* __restrict__ uid,
                           float* __restrict__ TU, float* __restrict__ IU, float* __restrict__ KV) {
    int idx = blockIdx.x * blockDim.x + threadIdx.x;
    if (idx >= Bn * DFn) return;
    int b = idx / DFn, j = idx % DFn;
    float vt, vi;
    if (j < Dn) {
        vt = tg[((size_t)b * Ln) * Dn + j];
        vi = ig[((size_t)b * Ln) * Dn + j];
    } else {
        float u = ut[(size_t)uid[b] * DUn + (j - Dn)];
        vt = u;
        vi = u;
    }
    TU[idx] = vt;
    IU[idx] = vi;
    KV[((size_t)2 * b) * DFn + j] = vt;
    KV[((size_t)(2 * b + 1)) * DFn + j] = vi;
}

__global__ void fused_gemm(const float* __restrict__ TU, const float* __restrict__ IU,
                           const float* __restrict__ W3, const float* __restrict__ b3,
                           float* __restrict__ F) {
    int idx = blockIdx.x * blockDim.x + threadIdx.x;
    if (idx >= Bn * DFn) return;
    int b = idx / DFn, j = idx % DFn;
    float acc = b3[j];
    for (int k = 0; k < DFn; k++) acc += TU[(size_t)b * DFn + k] * W3[(size_t)k * DFn + j];
    for (int k = 0; k < DFn; k++) acc += IU[(size_t)b * DFn + k] * W3[(size_t)(DFn + k) * DFn + j];
    F[idx] = acc;
}

__global__ void small_gemm(const float* __restrict__ A, const float* __restrict__ W,
                           const float* __restrict__ bias, const float* __restrict__ res,
                           float* __restrict__ C, int M, int K, int Nc, int do_relu) {
    int idx = blockIdx.x * blockDim.x + threadIdx.x;
    if (idx >= M * Nc) return;
    int r = idx / Nc, c = idx % Nc;
    float acc = bias ? bias[c] : 0.f;
    for (int k = 0; k < K; k++) acc += A[(size_t)r * K + k] * W[(size_t)k * Nc + c];
    if (res) acc += res[idx];
    if (do_relu) acc = fmaxf(acc, 0.f);
    C[idx] = acc;
}

__global__ void attn_kernel(const float* __restrict__ Q, const float* __restrict__ Km,
                            const float* __restrict__ Vm, float* __restrict__ O) {
    int t = threadIdx.x;
    if (t >= Bn * 4) return;
    int b = t / 4, h = t % 4;
    const float* q = Q + (size_t)b * DFn + h * 96;
    const float* k0 = Km + (size_t)(2 * b) * DFn + h * 96;
    const float* k1 = Km + (size_t)(2 * b + 1) * DFn + h * 96;
    float s0 = 0.f, s1 = 0.f;
    for (int d = 0; d < 96; d++) {
        s0 += q[d] * k0[d];
        s1 += q[d] * k1[d];
    }
    const float sc = 0.10206207261596575f;  // 1/sqrt(96)
    s0 *= sc;
    s1 *= sc;
    float m = fmaxf(s0, s1);
    float e0 = expf(s0 - m), e1 = expf(s1 - m);
    float inv = 1.f / (e0 + e1);
    e0 *= inv;
    e1 *= inv;
    const float* v0 = Vm + (size_t)(2 * b) * DFn + h * 96;
    const float* v1 = Vm + (size_t)(2 * b + 1) * DFn + h * 96;
    float* o = O + (size_t)b * DFn + h * 96;
    for (int d = 0; d < 96; d++) o[d] = e0 * v0[d] + e1 * v1[d];
}

__global__ void final_kernel(const float* __restrict__ o3, const float* __restrict__ W4,
                             const float* __restrict__ b4, float* __restrict__ out) {
    int b = threadIdx.x;
    if (b >= Bn) return;
    float acc = b4[0];
    for (int k = 0; k < DFn; k++) acc += o3[(size_t)b * DFn + k] * W4[k];
    out[b] = acc;
}

// ---------------- launch ----------------
extern "C" void kernel_launch(void* const* d_in, const int* in_sizes, int n_in,
                              void* d_out, int out_size, void* d_ws, size_t ws_size,
                              hipStream_t stream) {
    const float* text_table = (const float*)d_in[2];
    const float* img_table  = (const float*)d_in[3];
    const float* W1 = (const float*)d_in[4];
    const float* b1 = (const float*)d_in[5];
    const float* W2 = (const float*)d_in[6];
    const float* b2 = (const float*)d_in[7];
    const float* user_table = (const float*)d_in[8];
    const float* Wt = (const float*)d_in[9];
    const float* bt = (const float*)d_in[10];
    const float* Wi = (const float*)d_in[11];
    const float* bi = (const float*)d_in[12];
    const float* Wq = (const float*)d_in[13];
    const float* Wk = (const float*)d_in[14];
    const float* Wv = (const float*)d_in[15];
    const float* Wo = (const float*)d_in[16];
    const float* W3 = (const float*)d_in[17];
    const float* b3 = (const float*)d_in[18];
    const float* Wd = (const float*)d_in[19];
    const float* bd = (const float*)d_in[20];
    const float* W4 = (const float*)d_in[21];
    const float* b4 = (const float*)d_in[22];
    const int* rel = (const int*)d_in[23];
    const int* uid = (const int*)d_in[24];
    const int* hg  = (const int*)d_in[25];
    const int* node_idx = hg;
    const int* edge_idx = hg + NNZn;

    float* ws = (float*)d_ws;
    float* tg   = ws;
    float* ig   = tg + NDl;
    float* y    = ig + NDl;
    float* e    = y + NDl;
    float* invE = e + (long)En * Dn;
    float* invN = invE + En;
    float* TU   = invN + Nn;
    float* IU   = TU + Bn * DFn;
    float* KV   = IU + Bn * DFn;
    float* F    = KV + 2 * Bn * DFn;
    float* Qm   = F + Bn * DFn;
    float* Kmat = Qm + Bn * DFn;
    float* Vmat = Kmat + 2 * Bn * DFn;
    float* O    = Vmat + 2 * Bn * DFn;
    float* o2   = O + Bn * DFn;
    float* o3   = o2 + Bn * DFn;
    float* outp = (float*)d_out;

    // degrees (invE and invN are contiguous: zero/recip both at once)
    zero_kernel<<<(En + Nn + 255) / 256, 256, 0, stream>>>(invE, En + Nn);
    count_deg<<<(NNZn + 255) / 256, 256, 0, stream>>>(node_idx, edge_idx, invN, invE, NNZn);
    recip_kernel<<<(En + Nn + 255) / 256, 256, 0, stream>>>(invE, En + Nn);

    dim3 blk(16, 16);
    dim3 grd(Dn / 64, Nn / 64);  // (4, 150)
    // te / ie projections with bias + PE
    gemm64<true><<<grd, blk, 0, stream>>>(text_table, rel, W1, b1, tg, Nn, 384, Dn, 3);
    gemm64<true><<<grd, blk, 0, stream>>>(img_table, rel, W2, b2, ig, Nn, 2048, Dn, 3);

    const int ED = En * Dn;
    for (int l = 0; l < 2; l++) {
        // tg conv
        gemm64<false><<<grd, blk, 0, stream>>>(tg, nullptr, Wt + (size_t)l * Dn * Dn, nullptr, y, Nn, Dn, Dn, 0);
        zero_kernel<<<(ED + 255) / 256, 256, 0, stream>>>(e, ED);
        scatter_edge<<<NNZn, Dn, 0, stream>>>(y, node_idx, edge_idx, e);
        zero_kernel<<<((int)NDl + 255) / 256, 256, 0, stream>>>(tg, (int)NDl);
        scatter_node<<<NNZn, Dn, 0, stream>>>(e, invE, node_idx, edge_idx, tg);
        finalize_node<<<((int)NDl + 255) / 256, 256, 0, stream>>>(tg, invN, bt + (size_t)l * Dn, (int)NDl);
        // ig conv
        gemm64<false><<<grd, blk, 0, stream>>>(ig, nullptr, Wi + (size_t)l * Dn * Dn, nullptr, y, Nn, Dn, Dn, 0);
        zero_kernel<<<(ED + 255) / 256, 256, 0, stream>>>(e, ED);
        scatter_edge<<<NNZn, Dn, 0, stream>>>(y, node_idx, edge_idx, e);
        zero_kernel<<<((int)NDl + 255) / 256, 256, 0, stream>>>(ig, (int)NDl);
        scatter_node<<<NNZn, Dn, 0, stream>>>(e, invE, node_idx, edge_idx, ig);
        finalize_node<<<((int)NDl + 255) / 256, 256, 0, stream>>>(ig, invN, bi + (size_t)l * Dn, (int)NDl);
    }

    build_user<<<(Bn * DFn + 255) / 256, 256, 0, stream>>>(tg, ig, user_table, uid, TU, IU, KV);
    fused_gemm<<<(Bn * DFn + 255) / 256, 256, 0, stream>>>(TU, IU, W3, b3, F);
    small_gemm<<<(Bn * DFn + 255) / 256, 256, 0, stream>>>(F, Wq, nullptr, nullptr, Qm, Bn, DFn, DFn, 0);
    small_gemm<<<(2 * Bn * DFn + 255) / 256, 256, 0, stream>>>(KV, Wk, nullptr, nullptr, Kmat, 2 * Bn, DFn, DFn, 0);
    small_gemm<<<(2 * Bn * DFn + 255) / 256, 256, 0, stream>>>(KV, Wv, nullptr, nullptr, Vmat, 2 * Bn, DFn, DFn, 0);
    attn_kernel<<<1, 128, 0, stream>>>(Qm, Kmat, Vmat, O);
    small_gemm<<<(Bn * DFn + 255) / 256, 256, 0, stream>>>(O, Wo, nullptr, F, o2, Bn, DFn, DFn, 0);
    small_gemm<<<(Bn * DFn + 255) / 256, 256, 0, stream>>>(o2, Wd, bd, nullptr, o3, Bn, DFn, DFn, 1);
    final_kernel<<<1, 64, 0, stream>>>(o3, W4, b4, outp);
}

// Round 2
// 863.411 us; speedup vs baseline: 1.8695x; 1.8695x over previous
//
#include <hip/hip_runtime.h>

// Problem constants
constexpr int Bn = 32, Ln = 300, Dn = 256;
constexpr int Nn = Bn * Ln;          // 9600
constexpr int En = 4000, NNZn = 100000;
constexpr int DUn = 128, DFn = 384;
constexpr long NDl = (long)Nn * Dn;  // 2457600

// ---------------- utility kernels ----------------
__global__ void zero_kernel(float* __restrict__ p, long n) {
    long i = (long)blockIdx.x * blockDim.x + threadIdx.x;
    if (i < n) p[i] = 0.f;
}

__global__ void count_deg_int(const int* __restrict__ node_idx, const int* __restrict__ edge_idx,
                              int* __restrict__ cnt_e, int* __restrict__ cnt_n, int nnz) {
    int k = blockIdx.x * blockDim.x + threadIdx.x;
    if (k < nnz) {
        atomicAdd(&cnt_e[edge_idx[k]], 1);
        atomicAdd(&cnt_n[node_idx[k]], 1);
    }
}

// single-block exclusive scan of two count arrays -> offsets, plus 1/max(cnt,1)
__device__ __forceinline__ void scan_one(const int* __restrict__ cnt, int* __restrict__ off,
                                         float* __restrict__ inv, int n) {
    __shared__ int wsum[4];
    int t = threadIdx.x;
    int lane = t & 63, w = t >> 6;
    if (t == 0) off[0] = 0;
    int run = 0;
    for (int base = 0; base < n; base += 256) {
        int idx = base + t;
        int v = (idx < n) ? cnt[idx] : 0;
        if (idx < n) inv[idx] = 1.f / fmaxf((float)v, 1.f);
        // wave inclusive scan
        int s = v;
#pragma unroll
        for (int o = 1; o < 64; o <<= 1) {
            int x = __shfl_up(s, o);
            if (lane >= o) s += x;
        }
        if (lane == 63) wsum[w] = s;
        __syncthreads();
        int woff = 0;
        for (int i = 0; i < w; i++) woff += wsum[i];
        if (idx < n) off[idx + 1] = run + woff + s;
        int tot = wsum[0] + wsum[1] + wsum[2] + wsum[3];
        __syncthreads();
        run += tot;
    }
    __syncthreads();
}

__global__ void scan_two(const int* __restrict__ cnt_e, const int* __restrict__ cnt_n,
                         int* __restrict__ off_e, int* __restrict__ off_n,
                         float* __restrict__ invE, float* __restrict__ invN) {
    scan_one(cnt_e, off_e, invE, En);
    scan_one(cnt_n, off_n, invN, Nn);
}

__global__ void fill_csr(const int* __restrict__ node_idx, const int* __restrict__ edge_idx,
                         const int* __restrict__ off_e, const int* __restrict__ off_n,
                         int* __restrict__ cur_e, int* __restrict__ cur_n,
                         int* __restrict__ memb_e, int* __restrict__ memb_n, int nnz) {
    int k = blockIdx.x * blockDim.x + threadIdx.x;
    if (k < nnz) {
        int n = node_idx[k], ed = edge_idx[k];
        int pe = atomicAdd(&cur_e[ed], 1);
        memb_e[off_e[ed] + pe] = n;
        int pn = atomicAdd(&cur_n[n], 1);
        memb_n[off_n[n] + pn] = ed;
    }
}

__global__ void pe_kernel(float* __restrict__ pe_tab) {
    int idx = blockIdx.x * blockDim.x + threadIdx.x;  // 300*256
    if (idx >= Ln * Dn) return;
    int l = idx / Dn, c = idx % Dn;
    float v = 0.f;
    if (l > 0) {
        int j2 = c >> 1;
        float div = expf(-0.07195578415606394f * (float)j2);
        float ang = (float)(l - 1) * div;
        v = 0.002f * ((c & 1) ? cosf(ang) : sinf(ang));
    }
    pe_tab[idx] = v;
}

// ---------------- 128x64 register-blocked GEMM core ----------------
// C[M,Nc] tile = A[M,K] @ B[K,Nc] over K range [k_beg,k_end).
// flags bit0: +bias[col] (lead chunk only); bit1: +pe_tab[(row%300)*256+col] (lead only)
// multi: accumulate via atomicAdd (C must be pre-zeroed)
template <bool GATHER>
__device__ __forceinline__ void gemm_core(
    const float* __restrict__ A, const int* __restrict__ rel,
    const float* __restrict__ Bw, const float* __restrict__ bias,
    const float* __restrict__ pe_tab, float* __restrict__ C,
    int K, int Nc, int k_beg, int k_end, int flags, bool multi, bool lead) {
    __shared__ float As[16][132];
    __shared__ float Bs[16][68];
    const int tid = threadIdx.x;
    const int tx = tid & 15;
    const int ty = tid >> 4;
    const int m0 = blockIdx.y * 128, n0 = blockIdx.x * 64;

    const int arow_l = tid >> 1;        // 0..127
    const int ak = (tid & 1) * 8;       // 0 or 8
    long arow = m0 + arow_l;
    if (GATHER) arow = rel[arow];
    const float* aptr = A + (size_t)arow * K + ak;
    const int bk = tid >> 4;            // 0..15
    const int bn = (tid & 15) * 4;      // 0..60
    const float* bptr = Bw + (size_t)bk * Nc + n0 + bn;

    float acc[8][4] = {};
    float4 a0 = *(const float4*)(aptr + k_beg);
    float4 a1 = *(const float4*)(aptr + k_beg + 4);
    float4 bv = *(const float4*)(bptr + (size_t)k_beg * Nc);
    for (int k0 = k_beg; k0 < k_end; k0 += 16) {
        As[ak + 0][arow_l] = a0.x;
        As[ak + 1][arow_l] = a0.y;
        As[ak + 2][arow_l] = a0.z;
        As[ak + 3][arow_l] = a0.w;
        As[ak + 4][arow_l] = a1.x;
        As[ak + 5][arow_l] = a1.y;
        As[ak + 6][arow_l] = a1.z;
        As[ak + 7][arow_l] = a1.w;
        *(float4*)&Bs[bk][bn] = bv;
        __syncthreads();
        int kn = k0 + 16;
        if (kn < k_end) {  // prefetch next tile while computing
            a0 = *(const float4*)(aptr + kn);
            a1 = *(const float4*)(aptr + kn + 4);
            bv = *(const float4*)(bptr + (size_t)kn * Nc);
        }
#pragma unroll
        for (int kk = 0; kk < 16; kk++) {
            float4 af0 = *(const float4*)&As[kk][ty * 8];
            float4 af1 = *(const float4*)&As[kk][ty * 8 + 4];
            float4 bf = *(const float4*)&Bs[kk][tx * 4];
            float a[8] = {af0.x, af0.y, af0.z, af0.w, af1.x, af1.y, af1.z, af1.w};
            float b[4] = {bf.x, bf.y, bf.z, bf.w};
#pragma unroll
            for (int i = 0; i < 8; i++)
#pragma unroll
                for (int j = 0; j < 4; j++) acc[i][j] += a[i] * b[j];
        }
        __syncthreads();
    }
#pragma unroll
    for (int i = 0; i < 8; i++) {
        int row = m0 + ty * 8 + i;
        int col0 = n0 + tx * 4;
        float v[4];
#pragma unroll
        for (int j = 0; j < 4; j++) {
            v[j] = acc[i][j];
            if (lead) {
                if (flags & 1) v[j] += bias[col0 + j];
                if (flags & 2) v[j] += pe_tab[(row % Ln) * Dn + col0 + j];
            }
        }
        float* cp = C + (size_t)row * Nc + col0;
        if (multi) {
            atomicAdd(cp + 0, v[0]);
            atomicAdd(cp + 1, v[1]);
            atomicAdd(cp + 2, v[2]);
            atomicAdd(cp + 3, v[3]);
        } else {
            *(float4*)cp = make_float4(v[0], v[1], v[2], v[3]);
        }
    }
}

template <bool GATHER>
__global__ __launch_bounds__(256) void gemm_splitk(
    const float* __restrict__ A, const int* __restrict__ rel,
    const float* __restrict__ Bw, const float* __restrict__ bias,
    const float* __restrict__ pe_tab, float* __restrict__ C,
    int K, int Nc, int kChunk, int flags) {
    int chunk = blockIdx.z;
    int k_beg = chunk * kChunk;
    int k_end = min(K, k_beg + kChunk);
    gemm_core<GATHER>(A, rel, Bw, bias, pe_tab, C, K, Nc, k_beg, k_end, flags,
                      gridDim.z > 1, chunk == 0);
}

// both modalities' conv GEMM in one launch (z selects)
__global__ __launch_bounds__(256) void gemm_pair(
    const float* __restrict__ A0, const float* __restrict__ A1,
    const float* __restrict__ B0, const float* __restrict__ B1,
    float* __restrict__ C0, float* __restrict__ C1, int K, int Nc) {
    const float* A = blockIdx.z ? A1 : A0;
    const float* Bw = blockIdx.z ? B1 : B0;
    float* C = blockIdx.z ? C1 : C0;
    gemm_core<false>(A, nullptr, Bw, nullptr, nullptr, C, K, Nc, 0, K, 0, false, true);
}

// ---------------- CSR gather kernels (no atomics) ----------------
__global__ void edge_gather(const float* __restrict__ y0, const float* __restrict__ y1,
                            const int* __restrict__ memb, const int* __restrict__ off,
                            const float* __restrict__ invE,
                            float* __restrict__ e0, float* __restrict__ e1) {
    int ed = blockIdx.x;
    const float* y = blockIdx.y ? y1 : y0;
    float* e = blockIdx.y ? e1 : e0;
    int d = threadIdx.x;
    int s = off[ed], t = off[ed + 1];
    float acc = 0.f;
    for (int i = s; i < t; i++) acc += y[(size_t)memb[i] * Dn + d];
    e[(size_t)ed * Dn + d] = acc * invE[ed];
}

__global__ void node_gather(const float* __restrict__ e0, const float* __restrict__ e1,
                            const int* __restrict__ memb, const int* __restrict__ off,
                            const float* __restrict__ invN,
                            const float* __restrict__ bias0, const float* __restrict__ bias1,
                            float* __restrict__ o0, float* __restrict__ o1) {
    int n = blockIdx.x;
    const float* e = blockIdx.y ? e1 : e0;
    const float* bias = blockIdx.y ? bias1 : bias0;
    float* o = blockIdx.y ? o1 : o0;
    int d = threadIdx.x;
    int s = off[n], t = off[n + 1];
    float acc = 0.f;
    for (int i = s; i < t; i++) acc += e[(size_t)memb[i] * Dn + d];
    o[(size_t)n * Dn + d] = acc * invN[n] + bias[d];
}

// ---------------- tail kernels ----------------
__global__ void build_user(const float* __restrict__ tg, const float* __restrict__ ig,
                           const float* __restrict__ ut, const int* __restrict__ uid,
                           float* __restrict__ TU, float* __restrict__ IU, float* __restrict__ KV) {
    int idx = blockIdx.x * blockDim.x + threadIdx.x;
    if (idx >= Bn * DFn) return;
    int b = idx / DFn, j = idx % DFn;
    float vt, vi;
    if (j < Dn) {
        vt = tg[((size_t)b * Ln) * Dn + j];
        vi = ig[((size_t)b * Ln) * Dn + j];
    } else {
        float u = ut[(size_t)uid[b] * DUn + (j - Dn)];
        vt = u;
        vi = u;
    }
    TU[idx] = vt;
    IU[idx] = vi;
    KV[((size_t)2 * b) * DFn + j] = vt;
    KV[((size_t)(2 * b + 1)) * DFn + j] = vi;
}

__global__ void fused_gemm(const float* __restrict__ TU, const float* __restrict__ IU,
                           const float* __restrict__ W3, const float* __restrict__ b3,
                           float* __restrict__ F) {
    int idx = blockIdx.x * blockDim.x + threadIdx.x;
    if (idx >= Bn * DFn) return;
    int b = idx / DFn, j = idx % DFn;
    float acc = b3[j];
    for (int k = 0; k < DFn; k++) acc += TU[(size_t)b * DFn + k] * W3[(size_t)k * DFn + j];
    for (int k = 0; k < DFn; k++) acc += IU[(size_t)b * DFn + k] * W3[(size_t)(DFn + k) * DFn + j];
    F[idx] = acc;
}

__global__ void qkv_gemm(const float* __restrict__ F, const float* __restrict__ KV,
                         const float* __restrict__ Wq, const float* __restrict__ Wk,
                         const float* __restrict__ Wv, float* __restrict__ Qm,
                         float* __restrict__ Kmat, float* __restrict__ Vmat) {
    int idx = blockIdx.x * blockDim.x + threadIdx.x;
    if (idx >= 160 * DFn) return;
    int r = idx / DFn, c = idx % DFn;
    const float* A;
    const float* W;
    float* C;
    int ar;
    if (r < 32) { A = F; W = Wq; C = Qm; ar = r; }
    else if (r < 96) { A = KV; W = Wk; C = Kmat; ar = r - 32; }
    else { A = KV; W = Wv; C = Vmat; ar = r - 96; }
    float acc = 0.f;
    for (int k = 0; k < DFn; k++) acc += A[(size_t)ar * DFn + k] * W[(size_t)k * DFn + c];
    C[(size_t)ar * DFn + c] = acc;
}

__global__ void small_gemm(const float* __restrict__ A, const float* __restrict__ W,
                           const float* __restrict__ bias, const float* __restrict__ res,
                           float* __restrict__ C, int M, int K, int Nc, int do_relu) {
    int idx = blockIdx.x * blockDim.x + threadIdx.x;
    if (idx >= M * Nc) return;
    int r = idx / Nc, c = idx % Nc;
    float acc = bias ? bias[c] : 0.f;
    for (int k = 0; k < K; k++) acc += A[(size_t)r * K + k] * W[(size_t)k * Nc + c];
    if (res) acc += res[idx];
    if (do_relu) acc = fmaxf(acc, 0.f);
    C[idx] = acc;
}

__global__ void attn_kernel(const float* __restrict__ Q, const float* __restrict__ Km,
                            const float* __restrict__ Vm, float* __restrict__ O) {
    int t = threadIdx.x;
    if (t >= Bn * 4) return;
    int b = t / 4, h = t % 4;
    const float* q = Q + (size_t)b * DFn + h * 96;
    const float* k0 = Km + (size_t)(2 * b) * DFn + h * 96;
    const float* k1 = Km + (size_t)(2 * b + 1) * DFn + h * 96;
    float s0 = 0.f, s1 = 0.f;
    for (int d = 0; d < 96; d++) {
        s0 += q[d] * k0[d];
        s1 += q[d] * k1[d];
    }
    const float sc = 0.10206207261596575f;  // 1/sqrt(96)
    s0 *= sc;
    s1 *= sc;
    float m = fmaxf(s0, s1);
    float e0 = expf(s0 - m), e1 = expf(s1 - m);
    float inv = 1.f / (e0 + e1);
    e0 *= inv;
    e1 *= inv;
    const float* v0 = Vm + (size_t)(2 * b) * DFn + h * 96;
    const float* v1 = Vm + (size_t)(2 * b + 1) * DFn + h * 96;
    float* o = O + (size_t)b * DFn + h * 96;
    for (int d = 0; d < 96; d++) o[d] = e0 * v0[d] + e1 * v1[d];
}

__global__ void final_kernel(const float* __restrict__ o3, const float* __restrict__ W4,
                             const float* __restrict__ b4, float* __restrict__ out) {
    int b = threadIdx.x;
    if (b >= Bn) return;
    float acc = b4[0];
    for (int k = 0; k < DFn; k++) acc += o3[(size_t)b * DFn + k] * W4[k];
    out[b] = acc;
}

// ---------------- launch ----------------
extern "C" void kernel_launch(void* const* d_in, const int* in_sizes, int n_in,
                              void* d_out, int out_size, void* d_ws, size_t ws_size,
                              hipStream_t stream) {
    const float* text_table = (const float*)d_in[2];
    const float* img_table  = (const float*)d_in[3];
    const float* W1 = (const float*)d_in[4];
    const float* b1 = (const float*)d_in[5];
    const float* W2 = (const float*)d_in[6];
    const float* b2 = (const float*)d_in[7];
    const float* user_table = (const float*)d_in[8];
    const float* Wt = (const float*)d_in[9];
    const float* bt = (const float*)d_in[10];
    const float* Wi = (const float*)d_in[11];
    const float* bi = (const float*)d_in[12];
    const float* Wq = (const float*)d_in[13];
    const float* Wk = (const float*)d_in[14];
    const float* Wv = (const float*)d_in[15];
    const float* Wo = (const float*)d_in[16];
    const float* W3 = (const float*)d_in[17];
    const float* b3 = (const float*)d_in[18];
    const float* Wd = (const float*)d_in[19];
    const float* bd = (const float*)d_in[20];
    const float* W4 = (const float*)d_in[21];
    const float* b4 = (const float*)d_in[22];
    const int* rel = (const int*)d_in[23];
    const int* uid = (const int*)d_in[24];
    const int* hg  = (const int*)d_in[25];
    const int* node_idx = hg;
    const int* edge_idx = hg + NNZn;

    float* ws = (float*)d_ws;
    float* tg   = ws;                       // N*D
    float* ig   = tg + NDl;                 // N*D  (contiguous with tg)
    float* y_t  = ig + NDl;                 // N*D
    float* y_i  = y_t + NDl;                // N*D
    float* e_t  = y_i + NDl;                // E*D
    float* e_i  = e_t + (long)En * Dn;      // E*D
    float* invE = e_i + (long)En * Dn;      // E
    float* invN = invE + En;                // N
    float* pe_tab = invN + Nn;              // L*D
    float* TU   = pe_tab + Ln * Dn;
    float* IU   = TU + Bn * DFn;
    float* KV   = IU + Bn * DFn;
    float* F    = KV + 2 * Bn * DFn;
    float* Qm   = F + Bn * DFn;
    float* Kmat = Qm + Bn * DFn;
    float* Vmat = Kmat + 2 * Bn * DFn;
    float* O    = Vmat + 2 * Bn * DFn;
    float* o2   = O + Bn * DFn;
    float* o3   = o2 + Bn * DFn;
    // int region
    int* ib     = (int*)(o3 + Bn * DFn);
    int* cnt_e  = ib;                       // E
    int* cnt_n  = cnt_e + En;               // N
    int* cur_e  = cnt_n + Nn;               // E
    int* cur_n  = cur_e + En;               // N
    int* off_e  = cur_n + Nn;               // E+1
    int* off_n  = off_e + En + 1;           // N+1
    int* memb_e = off_n + Nn + 1;           // NNZ (node ids per edge)
    int* memb_n = memb_e + NNZn;            // NNZ (edge ids per node)
    float* outp = (float*)d_out;

    // ---- CSR build ----
    zero_kernel<<<(2 * (En + Nn) + 255) / 256, 256, 0, stream>>>((float*)cnt_e, 2 * (En + Nn));
    count_deg_int<<<(NNZn + 255) / 256, 256, 0, stream>>>(node_idx, edge_idx, cnt_e, cnt_n, NNZn);
    scan_two<<<1, 256, 0, stream>>>(cnt_e, cnt_n, off_e, off_n, invE, invN);
    fill_csr<<<(NNZn + 255) / 256, 256, 0, stream>>>(node_idx, edge_idx, off_e, off_n,
                                                     cur_e, cur_n, memb_e, memb_n, NNZn);
    pe_kernel<<<(Ln * Dn + 255) / 256, 256, 0, stream>>>(pe_tab);

    // ---- projections (split-K, accumulate into pre-zeroed tg/ig) ----
    zero_kernel<<<(int)((2 * NDl + 255) / 256), 256, 0, stream>>>(tg, 2 * NDl);
    dim3 grdT(Dn / 64, Nn / 128, 2);  // text: K=384, 2 chunks of 192
    gemm_splitk<true><<<grdT, 256, 0, stream>>>(text_table, rel, W1, b1, pe_tab, tg, 384, Dn, 192, 3);
    dim3 grdI(Dn / 64, Nn / 128, 4);  // img: K=2048, 4 chunks of 512
    gemm_splitk<true><<<grdI, 256, 0, stream>>>(img_table, rel, W2, b2, pe_tab, ig, 2048, Dn, 512, 3);

    // ---- hypergraph conv layers ----
    dim3 grdP(Dn / 64, Nn / 128, 2);
    for (int l = 0; l < 2; l++) {
        gemm_pair<<<grdP, 256, 0, stream>>>(tg, ig, Wt + (size_t)l * Dn * Dn,
                                            Wi + (size_t)l * Dn * Dn, y_t, y_i, Dn, Dn);
        edge_gather<<<dim3(En, 2), Dn, 0, stream>>>(y_t, y_i, memb_e, off_e, invE, e_t, e_i);
        node_gather<<<dim3(Nn, 2), Dn, 0, stream>>>(e_t, e_i, memb_n, off_n, invN,
                                                    bt + (size_t)l * Dn, bi + (size_t)l * Dn,
                                                    tg, ig);
    }

    // ---- tail ----
    build_user<<<(Bn * DFn + 255) / 256, 256, 0, stream>>>(tg, ig, user_table, uid, TU, IU, KV);
    fused_gemm<<<(Bn * DFn + 255) / 256, 256, 0, stream>>>(TU, IU, W3, b3, F);
    qkv_gemm<<<(160 * DFn + 255) / 256, 256, 0, stream>>>(F, KV, Wq, Wk, Wv, Qm, Kmat, Vmat);
    attn_kernel<<<1, 128, 0, stream>>>(Qm, Kmat, Vmat, O);
    small_gemm<<<(Bn * DFn + 255) / 256, 256, 0, stream>>>(O, Wo, nullptr, F, o2, Bn, DFn, DFn, 0);
    small_gemm<<<(Bn * DFn + 255) / 256, 256, 0, stream>>>(o2, Wd, bd, nullptr, o3, Bn, DFn, DFn, 1);
    final_kernel<<<1, 64, 0, stream>>>(o3, W4, b4, outp);
}

// Round 3
// 592.359 us; speedup vs baseline: 2.7249x; 1.4576x over previous
//
#include <hip/hip_runtime.h>

typedef unsigned short u16;
typedef unsigned int u32;
typedef __bf16 bf16x8 __attribute__((ext_vector_type(8)));
typedef float f32x4 __attribute__((ext_vector_type(4)));

// Problem constants
constexpr int Bn = 32, Ln = 300, Dn = 256;
constexpr int Nn = Bn * Ln;          // 9600
constexpr int En = 4000, NNZn = 100000;
constexpr int DUn = 128, DFn = 384;
constexpr long NDl = (long)Nn * Dn;  // 2457600
constexpr long EDl = (long)En * Dn;  // 1024000

__device__ __forceinline__ u16 f2bf(float f) {
    union { float f; u32 u; } x{f};
    u32 u = x.u;
    u32 r = (u + 0x7FFFu + ((u >> 16) & 1u)) >> 16;
    return (u16)r;
}
__device__ __forceinline__ float bf2f(u16 s) {
    union { u32 u; float f; } x{(u32)s << 16};
    return x.f;
}

// ---------------- utility kernels ----------------
__global__ void zero_kernel(float* __restrict__ p, long n) {
    long i = (long)blockIdx.x * blockDim.x + threadIdx.x;
    if (i < n) p[i] = 0.f;
}

__global__ void count_deg_int(const int* __restrict__ node_idx, const int* __restrict__ edge_idx,
                              int* __restrict__ cnt_e, int* __restrict__ cnt_n, int nnz) {
    int k = blockIdx.x * blockDim.x + threadIdx.x;
    if (k < nnz) {
        atomicAdd(&cnt_e[edge_idx[k]], 1);
        atomicAdd(&cnt_n[node_idx[k]], 1);
    }
}

__device__ __forceinline__ void scan_one(const int* __restrict__ cnt, int* __restrict__ off,
                                         float* __restrict__ inv, int n) {
    __shared__ int wsum[4];
    int t = threadIdx.x;
    int lane = t & 63, w = t >> 6;
    if (t == 0) off[0] = 0;
    int run = 0;
    for (int base = 0; base < n; base += 256) {
        int idx = base + t;
        int v = (idx < n) ? cnt[idx] : 0;
        if (idx < n) inv[idx] = 1.f / fmaxf((float)v, 1.f);
        int s = v;
#pragma unroll
        for (int o = 1; o < 64; o <<= 1) {
            int x = __shfl_up(s, o);
            if (lane >= o) s += x;
        }
        if (lane == 63) wsum[w] = s;
        __syncthreads();
        int woff = 0;
        for (int i = 0; i < w; i++) woff += wsum[i];
        if (idx < n) off[idx + 1] = run + woff + s;
        int tot = wsum[0] + wsum[1] + wsum[2] + wsum[3];
        __syncthreads();
        run += tot;
    }
    __syncthreads();
}

__global__ void scan_two(const int* __restrict__ cnt_e, const int* __restrict__ cnt_n,
                         int* __restrict__ off_e, int* __restrict__ off_n,
                         float* __restrict__ invE, float* __restrict__ invN) {
    scan_one(cnt_e, off_e, invE, En);
    scan_one(cnt_n, off_n, invN, Nn);
}

__global__ void fill_csr(const int* __restrict__ node_idx, const int* __restrict__ edge_idx,
                         const int* __restrict__ off_e, const int* __restrict__ off_n,
                         int* __restrict__ cur_e, int* __restrict__ cur_n,
                         int* __restrict__ memb_e, int* __restrict__ memb_n, int nnz) {
    int k = blockIdx.x * blockDim.x + threadIdx.x;
    if (k < nnz) {
        int n = node_idx[k], ed = edge_idx[k];
        int pe = atomicAdd(&cur_e[ed], 1);
        memb_e[off_e[ed] + pe] = n;
        int pn = atomicAdd(&cur_n[n], 1);
        memb_n[off_n[n] + pn] = ed;
    }
}

__global__ void pe_kernel(float* __restrict__ pe_tab) {
    int idx = blockIdx.x * blockDim.x + threadIdx.x;
    if (idx >= Ln * Dn) return;
    int l = idx / Dn, c = idx % Dn;
    float v = 0.f;
    if (l > 0) {
        int j2 = c >> 1;
        float div = expf(-0.07195578415606394f * (float)j2);
        float ang = (float)(l - 1) * div;
        v = 0.002f * ((c & 1) ? cosf(ang) : sinf(ang));
    }
    pe_tab[idx] = v;
}

// weight transpose + convert: Wt[n*K+k] = bf16(W[k*N+n])
__global__ void wT_kernel(const float* __restrict__ W, u16* __restrict__ Wt, int K, int N) {
    int idx = blockIdx.x * blockDim.x + threadIdx.x;
    if (idx >= K * N) return;
    int k = idx / N, n = idx % N;
    Wt[(size_t)n * K + k] = f2bf(W[idx]);
}

// fp32 -> bf16 convert (n divisible by 4)
__global__ void cvt_kernel(const float* __restrict__ in, u16* __restrict__ out, long n) {
    long i = ((long)blockIdx.x * blockDim.x + threadIdx.x) * 4;
    if (i < n) {
        float4 v = *(const float4*)&in[i];
        u16 o[4] = {f2bf(v.x), f2bf(v.y), f2bf(v.z), f2bf(v.w)};
        *(uint2*)&out[i] = *(uint2*)o;
    }
}

// ---------------- MFMA bf16 GEMM (BM=128, BN=128, BK=64, 4 waves) ----------------
// A: [M][K] (fp32 gathered via rel, or bf16 direct); Bt: [N][K] bf16 (pre-transposed)
// MODE 0: C fp32 atomicAdd (+bias+PE when lead)   MODE 1: C bf16 plain store
#define LOFF(row, kc) (((row) << 6) + ((((kc) ^ ((row) & 7))) << 3))

template <bool GATHER, int MODE>
__device__ __forceinline__ void gemm_core(
    const void* __restrict__ Aptr, const int* __restrict__ rel,
    const u16* __restrict__ Bt, const float* __restrict__ bias,
    const float* __restrict__ pe_tab, void* __restrict__ Cptr,
    int K, int kbeg, int kend, bool lead) {
    __shared__ u16 As[128 * 64];
    __shared__ u16 Bs[128 * 64];
    const int tid = threadIdx.x;
    const int lane = tid & 63;
    const int wv = tid >> 6;
    const int wr = wv >> 1, wc = wv & 1;
    const int m0 = blockIdx.y * 128;
    const int n0 = blockIdx.x * 128;

    f32x4 acc[4][4] = {};

    for (int k0 = kbeg; k0 < kend; k0 += 64) {
#pragma unroll
        for (int it = 0; it < 4; it++) {
            int cid = it * 256 + tid;
            int row = cid >> 3, kc = cid & 7;
            int gk = k0 + kc * 8;
            if (GATHER) {
                const float* Af = (const float*)Aptr;
                long grow = rel[m0 + row];
                const float* src = Af + grow * (long)K + gk;
                float4 f0 = *(const float4*)src;
                float4 f1 = *(const float4*)(src + 4);
                u16 tmp[8] = {f2bf(f0.x), f2bf(f0.y), f2bf(f0.z), f2bf(f0.w),
                              f2bf(f1.x), f2bf(f1.y), f2bf(f1.z), f2bf(f1.w)};
                *(uint4*)&As[LOFF(row, kc)] = *(uint4*)tmp;
            } else {
                const u16* Ab = (const u16*)Aptr;
                uint4 v = *(const uint4*)(Ab + (size_t)(m0 + row) * K + gk);
                *(uint4*)&As[LOFF(row, kc)] = v;
            }
        }
#pragma unroll
        for (int it = 0; it < 4; it++) {
            int cid = it * 256 + tid;
            int row = cid >> 3, kc = cid & 7;
            uint4 v = *(const uint4*)(Bt + (size_t)(n0 + row) * K + k0 + kc * 8);
            *(uint4*)&Bs[LOFF(row, kc)] = v;
        }
        __syncthreads();
#pragma unroll
        for (int ks = 0; ks < 2; ks++) {
            int kc = ks * 4 + (lane >> 4);
            bf16x8 a[4], b[4];
#pragma unroll
            for (int mf = 0; mf < 4; mf++) {
                int row = wr * 64 + mf * 16 + (lane & 15);
                a[mf] = *(bf16x8*)&As[LOFF(row, kc)];
            }
#pragma unroll
            for (int nf = 0; nf < 4; nf++) {
                int row = wc * 64 + nf * 16 + (lane & 15);
                b[nf] = *(bf16x8*)&Bs[LOFF(row, kc)];
            }
#pragma unroll
            for (int mf = 0; mf < 4; mf++)
#pragma unroll
                for (int nf = 0; nf < 4; nf++)
                    acc[mf][nf] = __builtin_amdgcn_mfma_f32_16x16x32_bf16(a[mf], b[nf], acc[mf][nf], 0, 0, 0);
        }
        __syncthreads();
    }

#pragma unroll
    for (int mf = 0; mf < 4; mf++) {
#pragma unroll
        for (int nf = 0; nf < 4; nf++) {
#pragma unroll
            for (int r = 0; r < 4; r++) {
                int row = m0 + wr * 64 + mf * 16 + (lane >> 4) * 4 + r;
                int col = n0 + wc * 64 + nf * 16 + (lane & 15);
                float v = acc[mf][nf][r];
                if (MODE == 0) {
                    float* C = (float*)Cptr;
                    if (lead) v += bias[col] + pe_tab[(row % Ln) * Dn + col];
                    atomicAdd(&C[(size_t)row * Dn + col], v);
                } else {
                    u16* C = (u16*)Cptr;
                    C[(size_t)row * Dn + col] = f2bf(v);
                }
            }
        }
    }
}

__global__ __launch_bounds__(256) void gemm_proj(
    const float* __restrict__ T, const int* __restrict__ rel,
    const u16* __restrict__ Bt, const float* __restrict__ bias,
    const float* __restrict__ pe_tab, float* __restrict__ C, int K, int kChunk) {
    int kb = blockIdx.z * kChunk;
    gemm_core<true, 0>(T, rel, Bt, bias, pe_tab, C, K, kb, kb + kChunk, blockIdx.z == 0);
}

__global__ __launch_bounds__(256) void gemm_conv(
    const u16* __restrict__ tgb, const u16* __restrict__ igb,
    const u16* __restrict__ Wtb, const u16* __restrict__ Wib,
    u16* __restrict__ y_t, u16* __restrict__ y_i) {
    const u16* A = blockIdx.z ? igb : tgb;
    const u16* Bt = blockIdx.z ? Wib : Wtb;
    u16* C = blockIdx.z ? y_i : y_t;
    gemm_core<false, 1>(A, nullptr, Bt, nullptr, nullptr, C, 256, 0, 256, false);
}

// ---------------- CSR gather kernels (bf16 payload, fp32 accum) ----------------
__global__ void edge_gather_b(const u16* __restrict__ y0, const u16* __restrict__ y1,
                              const int* __restrict__ memb, const int* __restrict__ off,
                              const float* __restrict__ invE,
                              u16* __restrict__ e0, u16* __restrict__ e1) {
    int ed = blockIdx.x;
    const u16* y = blockIdx.y ? y1 : y0;
    u16* e = blockIdx.y ? e1 : e0;
    int t = threadIdx.x;  // 128 threads, 2 cols each
    int s = off[ed], en = off[ed + 1];
    float a0 = 0.f, a1 = 0.f;
    for (int i = s; i < en; i++) {
        u32 v = *(const u32*)&y[(size_t)memb[i] * Dn + 2 * t];
        a0 += bf2f((u16)(v & 0xffff));
        a1 += bf2f((u16)(v >> 16));
    }
    float sc = invE[ed];
    u32 o = (u32)f2bf(a0 * sc) | ((u32)f2bf(a1 * sc) << 16);
    *(u32*)&e[(size_t)ed * Dn + 2 * t] = o;
}

__global__ void node_gather_b(const u16* __restrict__ e0, const u16* __restrict__ e1,
                              const int* __restrict__ memb, const int* __restrict__ off,
                              const float* __restrict__ invN,
                              const float* __restrict__ bias0, const float* __restrict__ bias1,
                              u16* __restrict__ o0, u16* __restrict__ o1) {
    int n = blockIdx.x;
    const u16* e = blockIdx.y ? e1 : e0;
    const float* bias = blockIdx.y ? bias1 : bias0;
    u16* o = blockIdx.y ? o1 : o0;
    int t = threadIdx.x;  // 128 threads, 2 cols each
    int s = off[n], en = off[n + 1];
    float a0 = 0.f, a1 = 0.f;
    for (int i = s; i < en; i++) {
        u32 v = *(const u32*)&e[(size_t)memb[i] * Dn + 2 * t];
        a0 += bf2f((u16)(v & 0xffff));
        a1 += bf2f((u16)(v >> 16));
    }
    float sc = invN[n];
    u32 ov = (u32)f2bf(a0 * sc + bias[2 * t]) | ((u32)f2bf(a1 * sc + bias[2 * t + 1]) << 16);
    *(u32*)&o[(size_t)n * Dn + 2 * t] = ov;
}

// ---------------- tail kernels (fp32) ----------------
__global__ void build_user(const u16* __restrict__ tgb, const u16* __restrict__ igb,
                           const float* __restrict__ ut, const int* __restrict__ uid,
                           float* __restrict__ TU, float* __restrict__ IU, float* __restrict__ KV) {
    int idx = blockIdx.x * blockDim.x + threadIdx.x;
    if (idx >= Bn * DFn) return;
    int b = idx / DFn, j = idx % DFn;
    float vt, vi;
    if (j < Dn) {
        vt = bf2f(tgb[((size_t)b * Ln) * Dn + j]);
        vi = bf2f(igb[((size_t)b * Ln) * Dn + j]);
    } else {
        float u = ut[(size_t)uid[b] * DUn + (j - Dn)];
        vt = u;
        vi = u;
    }
    TU[idx] = vt;
    IU[idx] = vi;
    KV[((size_t)2 * b) * DFn + j] = vt;
    KV[((size_t)(2 * b + 1)) * DFn + j] = vi;
}

__global__ void fused_gemm(const float* __restrict__ TU, const float* __restrict__ IU,
                           const float* __restrict__ W3, const float* __restrict__ b3,
                           float* __restrict__ F) {
    int idx = blockIdx.x * blockDim.x + threadIdx.x;
    if (idx >= Bn * DFn) return;
    int b = idx / DFn, j = idx % DFn;
    float acc = b3[j];
    for (int k = 0; k < DFn; k++) acc += TU[(size_t)b * DFn + k] * W3[(size_t)k * DFn + j];
    for (int k = 0; k < DFn; k++) acc += IU[(size_t)b * DFn + k] * W3[(size_t)(DFn + k) * DFn + j];
    F[idx] = acc;
}

__global__ void qkv_gemm(const float* __restrict__ F, const float* __restrict__ KV,
                         const float* __restrict__ Wq, const float* __restrict__ Wk,
                         const float* __restrict__ Wv, float* __restrict__ Qm,
                         float* __restrict__ Kmat, float* __restrict__ Vmat) {
    int idx = blockIdx.x * blockDim.x + threadIdx.x;
    if (idx >= 160 * DFn) return;
    int r = idx / DFn, c = idx % DFn;
    const float* A;
    const float* W;
    float* C;
    int ar;
    if (r < 32) { A = F; W = Wq; C = Qm; ar = r; }
    else if (r < 96) { A = KV; W = Wk; C = Kmat; ar = r - 32; }
    else { A = KV; W = Wv; C = Vmat; ar = r - 96; }
    float acc = 0.f;
    for (int k = 0; k < DFn; k++) acc += A[(size_t)ar * DFn + k] * W[(size_t)k * DFn + c];
    C[(size_t)ar * DFn + c] = acc;
}

__global__ void small_gemm(const float* __restrict__ A, const float* __restrict__ W,
                           const float* __restrict__ bias, const float* __restrict__ res,
                           float* __restrict__ C, int M, int K, int Nc, int do_relu) {
    int idx = blockIdx.x * blockDim.x + threadIdx.x;
    if (idx >= M * Nc) return;
    int r = idx / Nc, c = idx % Nc;
    float acc = bias ? bias[c] : 0.f;
    for (int k = 0; k < K; k++) acc += A[(size_t)r * K + k] * W[(size_t)k * Nc + c];
    if (res) acc += res[idx];
    if (do_relu) acc = fmaxf(acc, 0.f);
    C[idx] = acc;
}

__global__ void attn_kernel(const float* __restrict__ Q, const float* __restrict__ Km,
                            const float* __restrict__ Vm, float* __restrict__ O) {
    int t = threadIdx.x;
    if (t >= Bn * 4) return;
    int b = t / 4, h = t % 4;
    const float* q = Q + (size_t)b * DFn + h * 96;
    const float* k0 = Km + (size_t)(2 * b) * DFn + h * 96;
    const float* k1 = Km + (size_t)(2 * b + 1) * DFn + h * 96;
    float s0 = 0.f, s1 = 0.f;
    for (int d = 0; d < 96; d++) {
        s0 += q[d] * k0[d];
        s1 += q[d] * k1[d];
    }
    const float sc = 0.10206207261596575f;  // 1/sqrt(96)
    s0 *= sc;
    s1 *= sc;
    float m = fmaxf(s0, s1);
    float e0 = expf(s0 - m), e1 = expf(s1 - m);
    float inv = 1.f / (e0 + e1);
    e0 *= inv;
    e1 *= inv;
    const float* v0 = Vm + (size_t)(2 * b) * DFn + h * 96;
    const float* v1 = Vm + (size_t)(2 * b + 1) * DFn + h * 96;
    float* o = O + (size_t)b * DFn + h * 96;
    for (int d = 0; d < 96; d++) o[d] = e0 * v0[d] + e1 * v1[d];
}

__global__ void final_kernel(const float* __restrict__ o3, const float* __restrict__ W4,
                             const float* __restrict__ b4, float* __restrict__ out) {
    int b = threadIdx.x;
    if (b >= Bn) return;
    float acc = b4[0];
    for (int k = 0; k < DFn; k++) acc += o3[(size_t)b * DFn + k] * W4[k];
    out[b] = acc;
}

// ---------------- launch ----------------
extern "C" void kernel_launch(void* const* d_in, const int* in_sizes, int n_in,
                              void* d_out, int out_size, void* d_ws, size_t ws_size,
                              hipStream_t stream) {
    const float* text_table = (const float*)d_in[2];
    const float* img_table  = (const float*)d_in[3];
    const float* W1 = (const float*)d_in[4];
    const float* b1 = (const float*)d_in[5];
    const float* W2 = (const float*)d_in[6];
    const float* b2 = (const float*)d_in[7];
    const float* user_table = (const float*)d_in[8];
    const float* Wt = (const float*)d_in[9];
    const float* bt = (const float*)d_in[10];
    const float* Wi = (const float*)d_in[11];
    const float* bi = (const float*)d_in[12];
    const float* Wq = (const float*)d_in[13];
    const float* Wk = (const float*)d_in[14];
    const float* Wv = (const float*)d_in[15];
    const float* Wo = (const float*)d_in[16];
    const float* W3 = (const float*)d_in[17];
    const float* b3 = (const float*)d_in[18];
    const float* Wd = (const float*)d_in[19];
    const float* bd = (const float*)d_in[20];
    const float* W4 = (const float*)d_in[21];
    const float* b4 = (const float*)d_in[22];
    const int* rel = (const int*)d_in[23];
    const int* uid = (const int*)d_in[24];
    const int* hg  = (const int*)d_in[25];
    const int* node_idx = hg;
    const int* edge_idx = hg + NNZn;

    // ---- workspace layout ----
    float* tg32 = (float*)d_ws;             // NDl (contiguous with ig32 for zero+cvt)
    float* ig32 = tg32 + NDl;               // NDl
    u16* tgb = (u16*)(ig32 + NDl);          // NDl
    u16* igb = tgb + NDl;                   // NDl
    u16* y_t = igb + NDl;                   // NDl
    u16* y_i = y_t + NDl;                   // NDl
    u16* e_t = y_i + NDl;                   // E*D
    u16* e_i = e_t + EDl;                   // E*D
    u16* W1t = e_i + EDl;                   // 256*384
    u16* W2t = W1t + 256 * 384;             // 256*2048
    u16* Wtt = W2t + 256 * 2048;            // 2*256*256
    u16* Wit = Wtt + 2 * 256 * 256;         // 2*256*256
    float* invE = (float*)(Wit + 2 * 256 * 256);  // E
    float* invN = invE + En;                // N
    float* pe_tab = invN + Nn;              // L*D
    float* TU   = pe_tab + Ln * Dn;
    float* IU   = TU + Bn * DFn;
    float* KV   = IU + Bn * DFn;
    float* F    = KV + 2 * Bn * DFn;
    float* Qm   = F + Bn * DFn;
    float* Kmat = Qm + Bn * DFn;
    float* Vmat = Kmat + 2 * Bn * DFn;
    float* O    = Vmat + 2 * Bn * DFn;
    float* o2   = O + Bn * DFn;
    float* o3   = o2 + Bn * DFn;
    int* cnt_e  = (int*)(o3 + Bn * DFn);    // E
    int* cnt_n  = cnt_e + En;               // N
    int* cur_e  = cnt_n + Nn;               // E
    int* cur_n  = cur_e + En;               // N
    int* off_e  = cur_n + Nn;               // E+1
    int* off_n  = off_e + En + 1;           // N+1
    int* memb_e = off_n + Nn + 1;           // NNZ
    int* memb_n = memb_e + NNZn;            // NNZ
    float* outp = (float*)d_out;

    // ---- CSR build + PE + weight prep ----
    zero_kernel<<<(2 * (En + Nn) + 255) / 256, 256, 0, stream>>>((float*)cnt_e, 2 * (En + Nn));
    count_deg_int<<<(NNZn + 255) / 256, 256, 0, stream>>>(node_idx, edge_idx, cnt_e, cnt_n, NNZn);
    scan_two<<<1, 256, 0, stream>>>(cnt_e, cnt_n, off_e, off_n, invE, invN);
    fill_csr<<<(NNZn + 255) / 256, 256, 0, stream>>>(node_idx, edge_idx, off_e, off_n,
                                                     cur_e, cur_n, memb_e, memb_n, NNZn);
    pe_kernel<<<(Ln * Dn + 255) / 256, 256, 0, stream>>>(pe_tab);
    wT_kernel<<<(384 * 256 + 255) / 256, 256, 0, stream>>>(W1, W1t, 384, 256);
    wT_kernel<<<(2048 * 256 + 255) / 256, 256, 0, stream>>>(W2, W2t, 2048, 256);
    for (int l = 0; l < 2; l++) {
        wT_kernel<<<(256 * 256 + 255) / 256, 256, 0, stream>>>(Wt + (size_t)l * 65536, Wtt + (size_t)l * 65536, 256, 256);
        wT_kernel<<<(256 * 256 + 255) / 256, 256, 0, stream>>>(Wi + (size_t)l * 65536, Wit + (size_t)l * 65536, 256, 256);
    }

    // ---- projections: MFMA split-K=2, fp32 atomic accum, then convert to bf16 ----
    zero_kernel<<<(int)((2 * NDl + 255) / 256), 256, 0, stream>>>(tg32, 2 * NDl);
    dim3 grdP(2, 75, 2);
    gemm_proj<<<grdP, 256, 0, stream>>>(text_table, rel, W1t, b1, pe_tab, tg32, 384, 192);
    gemm_proj<<<grdP, 256, 0, stream>>>(img_table, rel, W2t, b2, pe_tab, ig32, 2048, 1024);
    cvt_kernel<<<(int)((2 * NDl / 4 + 255) / 256), 256, 0, stream>>>(tg32, tgb, 2 * NDl);

    // ---- hypergraph conv layers (bf16) ----
    dim3 grdC(2, 75, 2);
    for (int l = 0; l < 2; l++) {
        gemm_conv<<<grdC, 256, 0, stream>>>(tgb, igb, Wtt + (size_t)l * 65536, Wit + (size_t)l * 65536, y_t, y_i);
        edge_gather_b<<<dim3(En, 2), 128, 0, stream>>>(y_t, y_i, memb_e, off_e, invE, e_t, e_i);
        node_gather_b<<<dim3(Nn, 2), 128, 0, stream>>>(e_t, e_i, memb_n, off_n, invN,
                                                       bt + (size_t)l * Dn, bi + (size_t)l * Dn,
                                                       tgb, igb);
    }

    // ---- tail (fp32) ----
    build_user<<<(Bn * DFn + 255) / 256, 256, 0, stream>>>(tgb, igb, user_table, uid, TU, IU, KV);
    fused_gemm<<<(Bn * DFn + 255) / 256, 256, 0, stream>>>(TU, IU, W3, b3, F);
    qkv_gemm<<<(160 * DFn + 255) / 256, 256, 0, stream>>>(F, KV, Wq, Wk, Wv, Qm, Kmat, Vmat);
    attn_kernel<<<1, 128, 0, stream>>>(Qm, Kmat, Vmat, O);
    small_gemm<<<(Bn * DFn + 255) / 256, 256, 0, stream>>>(O, Wo, nullptr, F, o2, Bn, DFn, DFn, 0);
    small_gemm<<<(Bn * DFn + 255) / 256, 256, 0, stream>>>(o2, Wd, bd, nullptr, o3, Bn, DFn, DFn, 1);
    final_kernel<<<1, 64, 0, stream>>>(o3, W4, b4, outp);
}

// Round 4
// 430.813 us; speedup vs baseline: 3.7467x; 1.3750x over previous
//
#include <hip/hip_runtime.h>

typedef unsigned short u16;
typedef unsigned int u32;
typedef __bf16 bf16x8 __attribute__((ext_vector_type(8)));
typedef float f32x4 __attribute__((ext_vector_type(4)));

// Problem constants
constexpr int Bn = 32, Ln = 300, Dn = 256;
constexpr int Nn = Bn * Ln;          // 9600
constexpr int En = 4000, NNZn = 100000;
constexpr int DUn = 128, DFn = 384;
constexpr int PK = 512;              // packed row: [text 256 | img 256]
constexpr long NPl = (long)Nn * PK;  // 4915200
constexpr long EPl = (long)En * PK;  // 2048000

__device__ __forceinline__ u16 f2bf(float f) {
    union { float f; u32 u; } x{f};
    u32 u = x.u;
    u32 r = (u + 0x7FFFu + ((u >> 16) & 1u)) >> 16;
    return (u16)r;
}
__device__ __forceinline__ float bf2f(u16 s) {
    union { u32 u; float f; } x{(u32)s << 16};
    return x.f;
}

// ---------------- CSR build ----------------
__global__ void zero_kernel(int* __restrict__ p, int n) {
    int i = blockIdx.x * blockDim.x + threadIdx.x;
    if (i < n) p[i] = 0;
}

__global__ void count_deg_int(const int* __restrict__ node_idx, const int* __restrict__ edge_idx,
                              int* __restrict__ cnt_e, int* __restrict__ cnt_n, int nnz) {
    int k = blockIdx.x * blockDim.x + threadIdx.x;
    if (k < nnz) {
        atomicAdd(&cnt_e[edge_idx[k]], 1);
        atomicAdd(&cnt_n[node_idx[k]], 1);
    }
}

__device__ __forceinline__ void scan_one(const int* __restrict__ cnt, int* __restrict__ off,
                                         float* __restrict__ inv, int n) {
    __shared__ int wsum[4];
    int t = threadIdx.x;
    int lane = t & 63, w = t >> 6;
    if (t == 0) off[0] = 0;
    int run = 0;
    for (int base = 0; base < n; base += 256) {
        int idx = base + t;
        int v = (idx < n) ? cnt[idx] : 0;
        if (idx < n) inv[idx] = 1.f / fmaxf((float)v, 1.f);
        int s = v;
#pragma unroll
        for (int o = 1; o < 64; o <<= 1) {
            int x = __shfl_up(s, o);
            if (lane >= o) s += x;
        }
        if (lane == 63) wsum[w] = s;
        __syncthreads();
        int woff = 0;
        for (int i = 0; i < w; i++) woff += wsum[i];
        if (idx < n) off[idx + 1] = run + woff + s;
        int tot = wsum[0] + wsum[1] + wsum[2] + wsum[3];
        __syncthreads();
        run += tot;
    }
    __syncthreads();
}

__global__ void scan_two(const int* __restrict__ cnt_e, const int* __restrict__ cnt_n,
                         int* __restrict__ off_e, int* __restrict__ off_n,
                         float* __restrict__ invE, float* __restrict__ invN) {
    scan_one(cnt_e, off_e, invE, En);
    scan_one(cnt_n, off_n, invN, Nn);
}

__global__ void fill_csr(const int* __restrict__ node_idx, const int* __restrict__ edge_idx,
                         const int* __restrict__ off_e, const int* __restrict__ off_n,
                         int* __restrict__ cur_e, int* __restrict__ cur_n,
                         int* __restrict__ memb_e, int* __restrict__ memb_n, int nnz) {
    int k = blockIdx.x * blockDim.x + threadIdx.x;
    if (k < nnz) {
        int n = node_idx[k], ed = edge_idx[k];
        int pe = atomicAdd(&cur_e[ed], 1);
        memb_e[off_e[ed] + pe] = n;
        int pn = atomicAdd(&cur_n[n], 1);
        memb_n[off_n[n] + pn] = ed;
    }
}

// ---------------- precompute kernels ----------------
__global__ void pe_kernel(float* __restrict__ pe_tab) {
    int idx = blockIdx.x * blockDim.x + threadIdx.x;
    if (idx >= Ln * Dn) return;
    int l = idx / Dn, c = idx % Dn;
    float v = 0.f;
    if (l > 0) {
        int j2 = c >> 1;
        float div = expf(-0.07195578415606394f * (float)j2);
        float ang = (float)(l - 1) * div;
        v = 0.002f * ((c & 1) ? cosf(ang) : sinf(ang));
    }
    pe_tab[idx] = v;
}

// weight transpose + convert: Wt[n*K+k] = bf16(W[k*N+n]), N=256
__global__ void wT_kernel(const float* __restrict__ W, u16* __restrict__ Wt, int K) {
    int idx = blockIdx.x * blockDim.x + threadIdx.x;
    if (idx >= K * 256) return;
    int k = idx >> 8, n = idx & 255;
    Wt[(size_t)n * K + k] = f2bf(W[idx]);
}

// Collapsed conv weights: W12t[m][n*256+k] = bf16(sum_j Wm0[k][j]*Wm1[j][n])
// bias12[m][n] = sum_j bm0[j]*Wm1[j][n] + bm1[n];  bias2w[m][n] = bm1[n]
__global__ void wprod_kernel(const float* __restrict__ Wt, const float* __restrict__ bt,
                             const float* __restrict__ Wi, const float* __restrict__ bi,
                             u16* __restrict__ W12t, float* __restrict__ bias12,
                             float* __restrict__ bias2w) {
    int idx = blockIdx.x * 256 + threadIdx.x;  // 2*256*256
    int m = idx >> 16;
    int k = (idx >> 8) & 255;
    int n = idx & 255;
    const float* W0 = m ? Wi : Wt;
    const float* W1 = W0 + 65536;
    const float* b0 = m ? bi : bt;
    float acc = 0.f;
    for (int j = 0; j < 256; j++) acc += W0[k * 256 + j] * W1[j * 256 + n];
    W12t[((size_t)m << 16) + n * 256 + k] = f2bf(acc);
    if (k == 0) {
        float ba = 0.f;
        for (int j = 0; j < 256; j++) ba += b0[j] * W1[j * 256 + n];
        bias12[m * 256 + n] = ba + b0[256 + n];
        bias2w[m * 256 + n] = b0[256 + n];
    }
}

// ---------------- MFMA GEMM: BM=64, BN=256, BK=64, 4 waves ----------------
#define LOFF(row, kc) (((row) << 6) + ((((kc) ^ ((row) & 7))) << 3))

// MODE 0: A = fp32 table gathered via rel; epilogue +bias+PE; out packed bf16 at coloff0
// MODE 1: A = packed bf16 (z-modality slice); epilogue +bias12 (deg0 -> bias2); out packed
template <int MODE>
__global__ __launch_bounds__(256) void gemm_mfma(
    const float* __restrict__ Af, const u16* __restrict__ Ab, const int* __restrict__ rel,
    int K, const u16* __restrict__ Bt, const float* __restrict__ bias,
    const float* __restrict__ bias2, const int* __restrict__ cnt,
    const float* __restrict__ pe_tab, u16* __restrict__ Cout, int coloff0) {
    __shared__ u16 As[64 * 64];
    __shared__ u16 Bs[256 * 64];
    const int tid = threadIdx.x;
    const int lane = tid & 63;
    const int wv = tid >> 6;
    const int m0 = blockIdx.y * 64;
    const int z = (MODE == 1) ? blockIdx.z : 0;
    const int coloff = coloff0 + z * 256;
    const u16* BtZ = (MODE == 1) ? Bt + ((size_t)z << 16) : Bt;

    const int srow = tid >> 3;  // 0..31
    const int skc = tid & 7;    // 0..7
    const float* ap0f = nullptr;
    const float* ap1f = nullptr;
    const u16* ap0b = nullptr;
    const u16* ap1b = nullptr;
    if (MODE == 0) {
        long g0 = rel[m0 + srow];
        long g1 = rel[m0 + srow + 32];
        ap0f = Af + g0 * (long)K + skc * 8;
        ap1f = Af + g1 * (long)K + skc * 8;
    } else {
        ap0b = Ab + (size_t)(m0 + srow) * PK + coloff + skc * 8;
        ap1b = Ab + (size_t)(m0 + srow + 32) * PK + coloff + skc * 8;
    }

    f32x4 acc[4][4] = {};

    for (int k0 = 0; k0 < K; k0 += 64) {
        if (MODE == 0) {
            float4 f0 = *(const float4*)(ap0f + k0);
            float4 f1 = *(const float4*)(ap0f + k0 + 4);
            u16 t0[8] = {f2bf(f0.x), f2bf(f0.y), f2bf(f0.z), f2bf(f0.w),
                         f2bf(f1.x), f2bf(f1.y), f2bf(f1.z), f2bf(f1.w)};
            *(uint4*)&As[LOFF(srow, skc)] = *(uint4*)t0;
            float4 f2 = *(const float4*)(ap1f + k0);
            float4 f3 = *(const float4*)(ap1f + k0 + 4);
            u16 t1[8] = {f2bf(f2.x), f2bf(f2.y), f2bf(f2.z), f2bf(f2.w),
                         f2bf(f3.x), f2bf(f3.y), f2bf(f3.z), f2bf(f3.w)};
            *(uint4*)&As[LOFF(srow + 32, skc)] = *(uint4*)t1;
        } else {
            *(uint4*)&As[LOFF(srow, skc)] = *(const uint4*)(ap0b + k0);
            *(uint4*)&As[LOFF(srow + 32, skc)] = *(const uint4*)(ap1b + k0);
        }
#pragma unroll
        for (int it = 0; it < 8; it++) {
            int row = it * 32 + srow;
            *(uint4*)&Bs[LOFF(row, skc)] = *(const uint4*)(BtZ + (size_t)row * K + k0 + skc * 8);
        }
        __syncthreads();
#pragma unroll
        for (int ks = 0; ks < 2; ks++) {
            int kc = ks * 4 + (lane >> 4);
            bf16x8 a[4], b[4];
#pragma unroll
            for (int mf = 0; mf < 4; mf++) a[mf] = *(bf16x8*)&As[LOFF(mf * 16 + (lane & 15), kc)];
#pragma unroll
            for (int nf = 0; nf < 4; nf++)
                b[nf] = *(bf16x8*)&Bs[LOFF(wv * 64 + nf * 16 + (lane & 15), kc)];
#pragma unroll
            for (int mf = 0; mf < 4; mf++)
#pragma unroll
                for (int nf = 0; nf < 4; nf++)
                    acc[mf][nf] = __builtin_amdgcn_mfma_f32_16x16x32_bf16(a[mf], b[nf], acc[mf][nf], 0, 0, 0);
        }
        __syncthreads();
    }

#pragma unroll
    for (int mf = 0; mf < 4; mf++) {
#pragma unroll
        for (int nf = 0; nf < 4; nf++) {
#pragma unroll
            for (int r = 0; r < 4; r++) {
                int row = m0 + mf * 16 + (lane >> 4) * 4 + r;
                int col = wv * 64 + nf * 16 + (lane & 15);
                float v = acc[mf][nf][r];
                if (MODE == 0) {
                    v += bias[col] + pe_tab[(row % Ln) * Dn + col];
                } else {
                    v += bias[z * 256 + col];
                    if (cnt[row] == 0) v = bias2[z * 256 + col];
                }
                Cout[(size_t)row * PK + coloff + col] = f2bf(v);
            }
        }
    }
}

// ---------------- packed aggregation (one wave per row, uint4 lanes) ----------------
__global__ __launch_bounds__(256) void agg_kernel(
    const u16* __restrict__ src, u16* __restrict__ dst,
    const int* __restrict__ memb, const int* __restrict__ off,
    const float* __restrict__ inv, int nrows) {
    int row = blockIdx.x * 4 + (threadIdx.x >> 6);
    int lane = threadIdx.x & 63;
    if (row >= nrows) return;
    int s = off[row], t = off[row + 1];
    float acc[8] = {};
    const u16* base = src + lane * 8;
    for (int i = s; i < t; i++) {
        uint4 v = *(const uint4*)(base + (size_t)memb[i] * PK);
        u16 h[8];
        *(uint4*)h = v;
#pragma unroll
        for (int j = 0; j < 8; j++) acc[j] += bf2f(h[j]);
    }
    float sc = inv[row];
    u16 o[8];
#pragma unroll
    for (int j = 0; j < 8; j++) o[j] = f2bf(acc[j] * sc);
    *(uint4*)(dst + (size_t)row * PK + lane * 8) = *(uint4*)o;
}

// ---------------- tail ----------------
__global__ void build_kv(const u16* __restrict__ xg, const float* __restrict__ ut,
                         const int* __restrict__ uid, float* __restrict__ KV) {
    int idx = blockIdx.x * blockDim.x + threadIdx.x;
    if (idx >= 64 * DFn) return;
    int r = idx / DFn, j = idx % DFn;
    int b = r >> 1, mod = r & 1;
    float v;
    if (j < Dn) v = bf2f(xg[(size_t)(b * Ln) * PK + mod * 256 + j]);
    else v = ut[(size_t)uid[b] * DUn + (j - Dn)];
    KV[idx] = v;
}

__global__ void fkv_gemm(const float* __restrict__ KV, const float* __restrict__ W3,
                         const float* __restrict__ b3, const float* __restrict__ Wk,
                         const float* __restrict__ Wv, float* __restrict__ F,
                         float* __restrict__ Kmat, float* __restrict__ Vmat) {
    int idx = blockIdx.x * blockDim.x + threadIdx.x;
    if (idx >= 160 * DFn) return;
    int r = idx / DFn, c = idx % DFn;
    if (r < 32) {
        const float* t0 = KV + (size_t)(2 * r) * DFn;
        const float* t1 = KV + (size_t)(2 * r + 1) * DFn;
        float acc = b3[c];
        for (int k = 0; k < DFn; k++) acc += t0[k] * W3[(size_t)k * DFn + c];
        for (int k = 0; k < DFn; k++) acc += t1[k] * W3[(size_t)(DFn + k) * DFn + c];
        F[(size_t)r * DFn + c] = acc;
    } else if (r < 96) {
        int ar = r - 32;
        float acc = 0.f;
        for (int k = 0; k < DFn; k++) acc += KV[(size_t)ar * DFn + k] * Wk[(size_t)k * DFn + c];
        Kmat[(size_t)ar * DFn + c] = acc;
    } else {
        int ar = r - 96;
        float acc = 0.f;
        for (int k = 0; k < DFn; k++) acc += KV[(size_t)ar * DFn + k] * Wv[(size_t)k * DFn + c];
        Vmat[(size_t)ar * DFn + c] = acc;
    }
}

// per-b chain: Q -> attn -> Wo(+F) -> relu(Wd)+bd -> dot W4
__global__ __launch_bounds__(128) void tail_chain(
    const float* __restrict__ F, const float* __restrict__ Kmat, const float* __restrict__ Vmat,
    const float* __restrict__ Wq, const float* __restrict__ Wo, const float* __restrict__ Wd,
    const float* __restrict__ bd, const float* __restrict__ W4, const float* __restrict__ b4,
    float* __restrict__ out) {
    __shared__ float q[DFn], o[DFn], o2[DFn], sarr[8], wgt[8], red[2];
    int b = blockIdx.x, t = threadIdx.x;
    const float* Fb = F + (size_t)b * DFn;
    for (int c = t; c < DFn; c += 128) {
        float acc = 0.f;
        for (int k = 0; k < DFn; k++) acc += Fb[k] * Wq[(size_t)k * DFn + c];
        q[c] = acc;
    }
    __syncthreads();
    if (t < 8) {
        int h = t >> 1, wch = t & 1;
        const float* kp = Kmat + (size_t)(2 * b + wch) * DFn + h * 96;
        float s = 0.f;
        for (int d = 0; d < 96; d++) s += q[h * 96 + d] * kp[d];
        sarr[t] = s * 0.10206207261596575f;  // 1/sqrt(96)
    }
    __syncthreads();
    if (t < 4) {
        float s0 = sarr[2 * t], s1 = sarr[2 * t + 1];
        float m = fmaxf(s0, s1);
        float e0 = expf(s0 - m), e1 = expf(s1 - m);
        float inv = 1.f / (e0 + e1);
        wgt[2 * t] = e0 * inv;
        wgt[2 * t + 1] = e1 * inv;
    }
    __syncthreads();
    for (int c = t; c < DFn; c += 128) {
        int h = c / 96;
        o[c] = wgt[2 * h] * Vmat[(size_t)(2 * b) * DFn + c] +
               wgt[2 * h + 1] * Vmat[(size_t)(2 * b + 1) * DFn + c];
    }
    __syncthreads();
    for (int c = t; c < DFn; c += 128) {
        float acc = Fb[c];
        for (int k = 0; k < DFn; k++) acc += o[k] * Wo[(size_t)k * DFn + c];
        o2[c] = acc;
    }
    __syncthreads();
    for (int c = t; c < DFn; c += 128) {
        float acc = bd[c];
        for (int k = 0; k < DFn; k++) acc += o2[k] * Wd[(size_t)k * DFn + c];
        q[c] = fmaxf(acc, 0.f);  // reuse q as o3
    }
    __syncthreads();
    float p = 0.f;
    for (int c = t; c < DFn; c += 128) p += q[c] * W4[c];
#pragma unroll
    for (int offd = 32; offd; offd >>= 1) p += __shfl_down(p, offd, 64);
    if ((t & 63) == 0) red[t >> 6] = p;
    __syncthreads();
    if (t == 0) out[b] = red[0] + red[1] + b4[0];
}

// ---------------- launch ----------------
extern "C" void kernel_launch(void* const* d_in, const int* in_sizes, int n_in,
                              void* d_out, int out_size, void* d_ws, size_t ws_size,
                              hipStream_t stream) {
    const float* text_table = (const float*)d_in[2];
    const float* img_table  = (const float*)d_in[3];
    const float* W1 = (const float*)d_in[4];
    const float* b1 = (const float*)d_in[5];
    const float* W2 = (const float*)d_in[6];
    const float* b2 = (const float*)d_in[7];
    const float* user_table = (const float*)d_in[8];
    const float* Wt = (const float*)d_in[9];
    const float* bt = (const float*)d_in[10];
    const float* Wi = (const float*)d_in[11];
    const float* bi = (const float*)d_in[12];
    const float* Wq = (const float*)d_in[13];
    const float* Wk = (const float*)d_in[14];
    const float* Wv = (const float*)d_in[15];
    const float* Wo = (const float*)d_in[16];
    const float* W3 = (const float*)d_in[17];
    const float* b3 = (const float*)d_in[18];
    const float* Wd = (const float*)d_in[19];
    const float* bd = (const float*)d_in[20];
    const float* W4 = (const float*)d_in[21];
    const float* b4 = (const float*)d_in[22];
    const int* rel = (const int*)d_in[23];
    const int* uid = (const int*)d_in[24];
    const int* hg  = (const int*)d_in[25];
    const int* node_idx = hg;
    const int* edge_idx = hg + NNZn;

    // ---- workspace layout ----
    u16* xg  = (u16*)d_ws;            // N*PK packed [t|i]
    u16* eP  = xg + NPl;              // E*PK
    u16* zg  = eP + EPl;              // N*PK
    u16* W1t = zg + NPl;              // 256*384
    u16* W2t = W1t + 256 * 384;       // 256*2048
    u16* W12t = W2t + 256 * 2048;     // 2*256*256
    float* invE   = (float*)(W12t + 2 * 65536);  // E
    float* invN   = invE + En;        // N
    float* pe_tab = invN + Nn;        // L*D
    float* bias12 = pe_tab + Ln * Dn; // 2*256
    float* bias2w = bias12 + 512;     // 2*256
    float* KV   = bias2w + 512;       // 64*384
    float* F    = KV + 64 * DFn;      // 32*384
    float* Kmat = F + 32 * DFn;       // 64*384
    float* Vmat = Kmat + 64 * DFn;    // 64*384
    int* cnt_e  = (int*)(Vmat + 64 * DFn);  // E
    int* cnt_n  = cnt_e + En;         // N
    int* cur_e  = cnt_n + Nn;         // E
    int* cur_n  = cur_e + En;         // N
    int* off_e  = cur_n + Nn;         // E+1
    int* off_n  = off_e + En + 1;     // N+1
    int* memb_e = off_n + Nn + 1;     // NNZ
    int* memb_n = memb_e + NNZn;      // NNZ
    float* outp = (float*)d_out;

    // ---- CSR build + precompute ----
    zero_kernel<<<(2 * (En + Nn) + 255) / 256, 256, 0, stream>>>(cnt_e, 2 * (En + Nn));
    count_deg_int<<<(NNZn + 255) / 256, 256, 0, stream>>>(node_idx, edge_idx, cnt_e, cnt_n, NNZn);
    scan_two<<<1, 256, 0, stream>>>(cnt_e, cnt_n, off_e, off_n, invE, invN);
    fill_csr<<<(NNZn + 255) / 256, 256, 0, stream>>>(node_idx, edge_idx, off_e, off_n,
                                                     cur_e, cur_n, memb_e, memb_n, NNZn);
    pe_kernel<<<(Ln * Dn + 255) / 256, 256, 0, stream>>>(pe_tab);
    wT_kernel<<<(384 * 256 + 255) / 256, 256, 0, stream>>>(W1, W1t, 384);
    wT_kernel<<<(2048 * 256 + 255) / 256, 256, 0, stream>>>(W2, W2t, 2048);
    wprod_kernel<<<512, 256, 0, stream>>>(Wt, bt, Wi, bi, W12t, bias12, bias2w);

    // ---- projections -> packed bf16 xg (bias+PE fused) ----
    dim3 grdP(1, Nn / 64, 1);  // 150 blocks
    gemm_mfma<0><<<grdP, 256, 0, stream>>>(text_table, nullptr, rel, 384, W1t, b1,
                                           nullptr, nullptr, pe_tab, xg, 0);
    gemm_mfma<0><<<grdP, 256, 0, stream>>>(img_table, nullptr, rel, 2048, W2t, b2,
                                           nullptr, nullptr, pe_tab, xg, 256);

    // ---- collapsed hypergraph aggregation: zg = A^2 xg ----
    agg_kernel<<<En / 4, 256, 0, stream>>>(xg, eP, memb_e, off_e, invE, En);
    agg_kernel<<<Nn / 4, 256, 0, stream>>>(eP, zg, memb_n, off_n, invN, Nn);
    agg_kernel<<<En / 4, 256, 0, stream>>>(zg, eP, memb_e, off_e, invE, En);
    agg_kernel<<<Nn / 4, 256, 0, stream>>>(eP, zg, memb_n, off_n, invN, Nn);

    // ---- collapsed conv GEMM: xg = zg @ W12 + bias12 (deg0 -> bias2) ----
    dim3 grdC(1, Nn / 64, 2);
    gemm_mfma<1><<<grdC, 256, 0, stream>>>(nullptr, zg, nullptr, 256, W12t, bias12,
                                           bias2w, cnt_n, nullptr, xg, 0);

    // ---- tail ----
    build_kv<<<(64 * DFn + 255) / 256, 256, 0, stream>>>(xg, user_table, uid, KV);
    fkv_gemm<<<(160 * DFn + 255) / 256, 256, 0, stream>>>(KV, W3, b3, Wk, Wv, F, Kmat, Vmat);
    tail_chain<<<Bn, 128, 0, stream>>>(F, Kmat, Vmat, Wq, Wo, Wd, bd, W4, b4, outp);
}

// Round 5
// 416.117 us; speedup vs baseline: 3.8790x; 1.0353x over previous
//
#include <hip/hip_runtime.h>

typedef unsigned short u16;
typedef unsigned int u32;
typedef __bf16 bf16x8 __attribute__((ext_vector_type(8)));
typedef float f32x4 __attribute__((ext_vector_type(4)));

// Problem constants
constexpr int Bn = 32, Ln = 300, Dn = 256;
constexpr int Nn = Bn * Ln;          // 9600
constexpr int En = 4000, NNZn = 100000;
constexpr int DUn = 128, DFn = 384;
constexpr int PK = 512;              // packed row: [text 256 | img 256]
constexpr long NPl = (long)Nn * PK;  // 4915200
constexpr long EPl = (long)En * PK;  // 2048000
constexpr int PMAX = 1536;           // tail pair-list capacity

__device__ __forceinline__ u16 f2bf(float f) {
    union { float f; u32 u; } x{f};
    u32 u = x.u;
    u32 r = (u + 0x7FFFu + ((u >> 16) & 1u)) >> 16;
    return (u16)r;
}
__device__ __forceinline__ float bf2f(u16 s) {
    union { u32 u; float f; } x{(u32)s << 16};
    return x.f;
}

// ---------------- CSR build ----------------
__global__ void count_deg_int(const int* __restrict__ node_idx, const int* __restrict__ edge_idx,
                              int* __restrict__ cnt_e, int* __restrict__ cnt_n, int nnz) {
    int k = blockIdx.x * blockDim.x + threadIdx.x;
    if (k < nnz) {
        atomicAdd(&cnt_e[edge_idx[k]], 1);
        atomicAdd(&cnt_n[node_idx[k]], 1);
    }
}

__device__ __forceinline__ void scan_one(const int* __restrict__ cnt, int* __restrict__ off,
                                         float* __restrict__ inv, int n) {
    __shared__ int wsum[4];
    int t = threadIdx.x;
    int lane = t & 63, w = t >> 6;
    if (t == 0) off[0] = 0;
    int run = 0;
    for (int base = 0; base < n; base += 256) {
        int idx = base + t;
        int v = (idx < n) ? cnt[idx] : 0;
        if (idx < n) inv[idx] = 1.f / fmaxf((float)v, 1.f);
        int s = v;
#pragma unroll
        for (int o = 1; o < 64; o <<= 1) {
            int x = __shfl_up(s, o);
            if (lane >= o) s += x;
        }
        if (lane == 63) wsum[w] = s;
        __syncthreads();
        int woff = 0;
        for (int i = 0; i < w; i++) woff += wsum[i];
        if (idx < n) off[idx + 1] = run + woff + s;
        int tot = wsum[0] + wsum[1] + wsum[2] + wsum[3];
        __syncthreads();
        run += tot;
    }
    __syncthreads();
}

__global__ void scan_two(const int* __restrict__ cnt_e, const int* __restrict__ cnt_n,
                         int* __restrict__ off_e, int* __restrict__ off_n,
                         float* __restrict__ invE, float* __restrict__ invN) {
    scan_one(cnt_e, off_e, invE, En);
    scan_one(cnt_n, off_n, invN, Nn);
}

__global__ void fill_csr(const int* __restrict__ node_idx, const int* __restrict__ edge_idx,
                         const int* __restrict__ off_e, const int* __restrict__ off_n,
                         int* __restrict__ cur_e, int* __restrict__ cur_n,
                         int* __restrict__ memb_e, int* __restrict__ memb_n, int nnz) {
    int k = blockIdx.x * blockDim.x + threadIdx.x;
    if (k < nnz) {
        int n = node_idx[k], ed = edge_idx[k];
        int pe = atomicAdd(&cur_e[ed], 1);
        memb_e[off_e[ed] + pe] = n;
        int pn = atomicAdd(&cur_n[n], 1);
        memb_n[off_n[n] + pn] = ed;
    }
}

// ---------------- fused precompute (block-ranged) ----------------
// blocks: [0,107) zero cnts | [107,407) pe | [407,791) wT1 | [791,2839) wT2 | [2839,3351) wprod
__global__ __launch_bounds__(256) void prep_kernel(
    int* __restrict__ cnts, float* __restrict__ pe_tab,
    const float* __restrict__ W1, u16* __restrict__ W1t,
    const float* __restrict__ W2, u16* __restrict__ W2t,
    const float* __restrict__ Wt, const float* __restrict__ bt,
    const float* __restrict__ Wi, const float* __restrict__ bi,
    u16* __restrict__ W12t, float* __restrict__ bias12, float* __restrict__ bias2w) {
    int bid = blockIdx.x;
    int t = threadIdx.x;
    if (bid < 107) {
        int i = bid * 256 + t;
        if (i < 2 * (En + Nn)) cnts[i] = 0;
        return;
    }
    bid -= 107;
    if (bid < 300) {
        int idx = bid * 256 + t;  // 76800 exact
        int l = idx / Dn, c = idx % Dn;
        float v = 0.f;
        if (l > 0) {
            int j2 = c >> 1;
            float div = expf(-0.07195578415606394f * (float)j2);
            float ang = (float)(l - 1) * div;
            v = 0.002f * ((c & 1) ? cosf(ang) : sinf(ang));
        }
        pe_tab[idx] = v;
        return;
    }
    bid -= 300;
    if (bid < 384) {
        int idx = bid * 256 + t;  // 98304 exact
        int k = idx >> 8, n = idx & 255;
        W1t[(size_t)n * 384 + k] = f2bf(W1[idx]);
        return;
    }
    bid -= 384;
    if (bid < 2048) {
        int idx = bid * 256 + t;  // 524288 exact
        int k = idx >> 8, n = idx & 255;
        W2t[(size_t)n * 2048 + k] = f2bf(W2[idx]);
        return;
    }
    bid -= 2048;
    {
        int idx = bid * 256 + t;  // 131072 exact
        int m = idx >> 16;
        int k = (idx >> 8) & 255;
        int n = idx & 255;
        const float* W0 = m ? Wi : Wt;
        const float* Wl1 = W0 + 65536;
        const float* b0 = m ? bi : bt;
        float acc = 0.f;
        for (int j = 0; j < 256; j++) acc += W0[k * 256 + j] * Wl1[j * 256 + n];
        // k-major layout for coalesced tail GEMV
        W12t[((size_t)m << 16) + k * 256 + n] = f2bf(acc);
        if (k == 0) {
            float ba = 0.f;
            for (int j = 0; j < 256; j++) ba += b0[j] * Wl1[j * 256 + n];
            bias12[m * 256 + n] = ba + b0[256 + n];
            bias2w[m * 256 + n] = b0[256 + n];
        }
    }
}

// ---------------- MFMA projection GEMM: BM=64, BN=256, BK=64, double-buffered ----
#define LOFF(row, kc) (((row) << 6) + ((((kc) ^ ((row) & 7))) << 3))

__global__ __launch_bounds__(256) void gemm_proj(
    const float* __restrict__ T0, const float* __restrict__ T1,
    const int* __restrict__ rel,
    const u16* __restrict__ W1t, const u16* __restrict__ W2t,
    const float* __restrict__ b1, const float* __restrict__ b2,
    const float* __restrict__ pe_tab, u16* __restrict__ xg) {
    __shared__ u16 As[64 * 64];
    __shared__ u16 Bs[256 * 64];
    const int tid = threadIdx.x;
    const int lane = tid & 63;
    const int wv = tid >> 6;
    const int m0 = blockIdx.y * 64;
    const int z = blockIdx.z;
    const int K = z ? 2048 : 384;
    const float* Af = z ? T1 : T0;
    const u16* Bt = z ? W2t : W1t;
    const float* bias = z ? b2 : b1;
    const int coloff = z ? 256 : 0;

    const int srow = tid >> 3;  // 0..31
    const int skc = tid & 7;    // 0..7
    long g0 = rel[m0 + srow];
    long g1 = rel[m0 + srow + 32];
    const float* ap0 = Af + g0 * (long)K + skc * 8;
    const float* ap1 = Af + g1 * (long)K + skc * 8;
    const u16* bp = Bt + (size_t)srow * K + skc * 8;

    f32x4 acc[4][4] = {};
    float4 ra0, ra1, rc0, rc1;
    uint4 rB[8];

    // prologue: load k0 = 0
    ra0 = *(const float4*)(ap0);
    ra1 = *(const float4*)(ap0 + 4);
    rc0 = *(const float4*)(ap1);
    rc1 = *(const float4*)(ap1 + 4);
#pragma unroll
    for (int it = 0; it < 8; it++) rB[it] = *(const uint4*)(bp + (size_t)(it * 32) * K);

    for (int k0 = 0; k0 < K; k0 += 64) {
        u16 ta[8] = {f2bf(ra0.x), f2bf(ra0.y), f2bf(ra0.z), f2bf(ra0.w),
                     f2bf(ra1.x), f2bf(ra1.y), f2bf(ra1.z), f2bf(ra1.w)};
        *(uint4*)&As[LOFF(srow, skc)] = *(uint4*)ta;
        u16 tb[8] = {f2bf(rc0.x), f2bf(rc0.y), f2bf(rc0.z), f2bf(rc0.w),
                     f2bf(rc1.x), f2bf(rc1.y), f2bf(rc1.z), f2bf(rc1.w)};
        *(uint4*)&As[LOFF(srow + 32, skc)] = *(uint4*)tb;
#pragma unroll
        for (int it = 0; it < 8; it++) *(uint4*)&Bs[LOFF(it * 32 + srow, skc)] = rB[it];
        __syncthreads();
        int kn = k0 + 64;
        if (kn < K) {  // prefetch next K-step into regs (overlaps MFMA below)
            ra0 = *(const float4*)(ap0 + kn);
            ra1 = *(const float4*)(ap0 + kn + 4);
            rc0 = *(const float4*)(ap1 + kn);
            rc1 = *(const float4*)(ap1 + kn + 4);
#pragma unroll
            for (int it = 0; it < 8; it++)
                rB[it] = *(const uint4*)(bp + (size_t)(it * 32) * K + kn);
        }
#pragma unroll
        for (int ks = 0; ks < 2; ks++) {
            int kc = ks * 4 + (lane >> 4);
            bf16x8 a[4], b[4];
#pragma unroll
            for (int mf = 0; mf < 4; mf++) a[mf] = *(bf16x8*)&As[LOFF(mf * 16 + (lane & 15), kc)];
#pragma unroll
            for (int nf = 0; nf < 4; nf++)
                b[nf] = *(bf16x8*)&Bs[LOFF(wv * 64 + nf * 16 + (lane & 15), kc)];
#pragma unroll
            for (int mf = 0; mf < 4; mf++)
#pragma unroll
                for (int nf = 0; nf < 4; nf++)
                    acc[mf][nf] = __builtin_amdgcn_mfma_f32_16x16x32_bf16(a[mf], b[nf], acc[mf][nf], 0, 0, 0);
        }
        __syncthreads();
    }

#pragma unroll
    for (int mf = 0; mf < 4; mf++) {
#pragma unroll
        for (int nf = 0; nf < 4; nf++) {
#pragma unroll
            for (int r = 0; r < 4; r++) {
                int row = m0 + mf * 16 + (lane >> 4) * 4 + r;
                int col = wv * 64 + nf * 16 + (lane & 15);
                float v = acc[mf][nf][r] + bias[col] + pe_tab[(row % Ln) * Dn + col];
                xg[(size_t)row * PK + coloff + col] = f2bf(v);
            }
        }
    }
}

// ---------------- packed aggregation (shfl-batched member indices) ----------------
__global__ __launch_bounds__(256) void agg_kernel(
    const u16* __restrict__ src, u16* __restrict__ dst,
    const int* __restrict__ memb, const int* __restrict__ off,
    const float* __restrict__ inv, int nrows) {
    int row = blockIdx.x * 4 + (threadIdx.x >> 6);
    int lane = threadIdx.x & 63;
    if (row >= nrows) return;
    int s = off[row], t = off[row + 1];
    float acc[8] = {};
    const u16* base = src + (size_t)lane * 8;
    for (int cb = s; cb < t; cb += 64) {
        int m = min(64, t - cb);
        int my = (lane < m) ? memb[cb + lane] : 0;
        for (int j = 0; j < m; j++) {
            int r = __builtin_amdgcn_readfirstlane(__shfl(my, j));
            uint4 v = *(const uint4*)(base + (size_t)r * PK);
            u16 h[8];
            *(uint4*)h = v;
#pragma unroll
            for (int q = 0; q < 8; q++) acc[q] += bf2f(h[q]);
        }
    }
    float sc = inv[row];
    u16 o[8];
#pragma unroll
    for (int j = 0; j < 8; j++) o[j] = f2bf(acc[j] * sc);
    *(uint4*)(dst + (size_t)row * PK + lane * 8) = *(uint4*)o;
}

// ---------------- fused tail: per-b agg3+agg4 + conv GEMV + KV + F/Q/K/V + attn + out ----
__global__ __launch_bounds__(256) void tail_all(
    const u16* __restrict__ zg, const u16* __restrict__ W12t,
    const float* __restrict__ bias12, const float* __restrict__ bias2w,
    const int* __restrict__ off_e, const int* __restrict__ memb_e,
    const int* __restrict__ off_n, const int* __restrict__ memb_n,
    const float* __restrict__ invE, const float* __restrict__ invN,
    const float* __restrict__ ut, const int* __restrict__ uid,
    const float* __restrict__ W3, const float* __restrict__ b3,
    const float* __restrict__ Wq, const float* __restrict__ Wk,
    const float* __restrict__ Wv, const float* __restrict__ Wo,
    const float* __restrict__ Wd, const float* __restrict__ bd,
    const float* __restrict__ W4, const float* __restrict__ b4,
    float* __restrict__ out) {
    __shared__ float zrow[PK];
    __shared__ float kv0[DFn], kv1[DFn], Fv[DFn], qv[DFn];
    __shared__ float K0[DFn], K1[DFn], V0[DFn], V1[DFn], ov[DFn], o2[DFn];
    __shared__ int plist[PMAX];
    __shared__ float pw[PMAX];
    __shared__ float sarr[8], wgt[8], red[4];
    __shared__ int pcount;

    int b = blockIdx.x, t = threadIdx.x;
    int r = b * Ln;
    int ns = off_n[r], ne = off_n[r + 1] - ns;

    // wave 0 builds flat (node, weight) pair list for the two-hop mean
    if (t < 64) {
        int e = (t < ne) ? memb_n[ns + t] : 0;
        int es = (t < ne) ? off_e[e] : 0;
        int em = (t < ne) ? off_e[e + 1] - es : 0;
        float w = (t < ne) ? invE[e] : 0.f;
        int pos = em;
#pragma unroll
        for (int o = 1; o < 64; o <<= 1) {
            int x = __shfl_up(pos, o);
            if (t >= o) pos += x;
        }
        int total = __shfl(pos, 63);
        pos -= em;  // exclusive prefix
        for (int j = 0; j < em; j++) {
            if (pos + j < PMAX) {
                plist[pos + j] = memb_e[es + j];
                pw[pos + j] = w;
            }
        }
        if (t == 0) pcount = min(total, PMAX);
    }
    __syncthreads();
    int P = pcount;

    // zrow = invN * sum_pairs w * zg[n]  (thread t covers cols 2t, 2t+1)
    {
        float za0 = 0.f, za1 = 0.f;
#pragma unroll 4
        for (int i = 0; i < P; i++) {
            int n = plist[i];
            float w = pw[i];
            u32 v = *(const u32*)&zg[(size_t)n * PK + 2 * t];
            za0 += bf2f((u16)(v & 0xffff)) * w;
            za1 += bf2f((u16)(v >> 16)) * w;
        }
        float sN = invN[r];
        zrow[2 * t] = za0 * sN;
        zrow[2 * t + 1] = za1 * sN;
    }
    __syncthreads();

    // conv GEMV: kv[c] = zrow[m] @ W12[m] + bias12 (deg0 -> bias2w); user part
    for (int c = t; c < 512; c += 256) {
        int m = c >> 8, cc = c & 255;
        float acc;
        if (ne == 0) {
            acc = bias2w[c];
        } else {
            acc = bias12[c];
            const u16* wp = W12t + ((size_t)m << 16) + cc;
            for (int k = 0; k < 256; k++) acc += zrow[m * 256 + k] * bf2f(wp[(size_t)k * 256]);
        }
        if (m == 0) kv0[cc] = acc;
        else kv1[cc] = acc;
    }
    if (t < 128) {
        float u = ut[(size_t)uid[b] * DUn + t];
        kv0[256 + t] = u;
        kv1[256 + t] = u;
    }
    __syncthreads();

    // F = [kv0 kv1] @ W3 + b3
    for (int c = t; c < DFn; c += 256) {
        float acc = b3[c];
        for (int k = 0; k < DFn; k++) acc += kv0[k] * W3[(size_t)k * DFn + c];
        for (int k = 0; k < DFn; k++) acc += kv1[k] * W3[(size_t)(DFn + k) * DFn + c];
        Fv[c] = acc;
    }
    __syncthreads();

    // Q, K0, K1, V0, V1
    for (int c = t; c < DFn; c += 256) {
        float aq = 0.f, ak0 = 0.f, ak1 = 0.f, av0 = 0.f, av1 = 0.f;
        for (int k = 0; k < DFn; k++) {
            float wk = Wk[(size_t)k * DFn + c];
            float wvv = Wv[(size_t)k * DFn + c];
            aq += Fv[k] * Wq[(size_t)k * DFn + c];
            ak0 += kv0[k] * wk;
            ak1 += kv1[k] * wk;
            av0 += kv0[k] * wvv;
            av1 += kv1[k] * wvv;
        }
        qv[c] = aq;
        K0[c] = ak0;
        K1[c] = ak1;
        V0[c] = av0;
        V1[c] = av1;
    }
    __syncthreads();

    // scores: 8 groups of 32 lanes, group g = (head h = g>>1, kv wch = g&1)
    {
        int g = t >> 5, l = t & 31;
        int h = g >> 1, wch = g & 1;
        const float* Kp = (wch ? K1 : K0) + h * 96;
        const float* qp = qv + h * 96;
        float p = 0.f;
        for (int d = l; d < 96; d += 32) p += qp[d] * Kp[d];
#pragma unroll
        for (int o = 16; o; o >>= 1) p += __shfl_down(p, o, 32);
        if (l == 0) sarr[g] = p * 0.10206207261596575f;  // 1/sqrt(96)
    }
    __syncthreads();
    if (t < 4) {
        float s0 = sarr[2 * t], s1 = sarr[2 * t + 1];
        float m = fmaxf(s0, s1);
        float e0 = expf(s0 - m), e1 = expf(s1 - m);
        float inv = 1.f / (e0 + e1);
        wgt[2 * t] = e0 * inv;
        wgt[2 * t + 1] = e1 * inv;
    }
    __syncthreads();
    for (int c = t; c < DFn; c += 256) {
        int h = c / 96;
        ov[c] = wgt[2 * h] * V0[c] + wgt[2 * h + 1] * V1[c];
    }
    __syncthreads();
    // o2 = ov @ Wo + F (residual is pre-Wq fused)
    for (int c = t; c < DFn; c += 256) {
        float acc = Fv[c];
        for (int k = 0; k < DFn; k++) acc += ov[k] * Wo[(size_t)k * DFn + c];
        o2[c] = acc;
    }
    __syncthreads();
    // o3 = relu(o2 @ Wd + bd) -> reuse qv
    for (int c = t; c < DFn; c += 256) {
        float acc = bd[c];
        for (int k = 0; k < DFn; k++) acc += o2[k] * Wd[(size_t)k * DFn + c];
        qv[c] = fmaxf(acc, 0.f);
    }
    __syncthreads();
    float p2 = 0.f;
    for (int c = t; c < DFn; c += 256) p2 += qv[c] * W4[c];
#pragma unroll
    for (int o = 32; o; o >>= 1) p2 += __shfl_down(p2, o);
    if ((t & 63) == 0) red[t >> 6] = p2;
    __syncthreads();
    if (t == 0) out[b] = red[0] + red[1] + red[2] + red[3] + b4[0];
}

// ---------------- launch ----------------
extern "C" void kernel_launch(void* const* d_in, const int* in_sizes, int n_in,
                              void* d_out, int out_size, void* d_ws, size_t ws_size,
                              hipStream_t stream) {
    const float* text_table = (const float*)d_in[2];
    const float* img_table  = (const float*)d_in[3];
    const float* W1 = (const float*)d_in[4];
    const float* b1 = (const float*)d_in[5];
    const float* W2 = (const float*)d_in[6];
    const float* b2 = (const float*)d_in[7];
    const float* user_table = (const float*)d_in[8];
    const float* Wt = (const float*)d_in[9];
    const float* bt = (const float*)d_in[10];
    const float* Wi = (const float*)d_in[11];
    const float* bi = (const float*)d_in[12];
    const float* Wq = (const float*)d_in[13];
    const float* Wk = (const float*)d_in[14];
    const float* Wv = (const float*)d_in[15];
    const float* Wo = (const float*)d_in[16];
    const float* W3 = (const float*)d_in[17];
    const float* b3 = (const float*)d_in[18];
    const float* Wd = (const float*)d_in[19];
    const float* bd = (const float*)d_in[20];
    const float* W4 = (const float*)d_in[21];
    const float* b4 = (const float*)d_in[22];
    const int* rel = (const int*)d_in[23];
    const int* uid = (const int*)d_in[24];
    const int* hg  = (const int*)d_in[25];
    const int* node_idx = hg;
    const int* edge_idx = hg + NNZn;

    // ---- workspace layout ----
    u16* xg  = (u16*)d_ws;            // N*PK packed [t|i]
    u16* eP  = xg + NPl;              // E*PK
    u16* zg  = eP + EPl;              // N*PK
    u16* W1t = zg + NPl;              // 256*384
    u16* W2t = W1t + 98304;           // 256*2048
    u16* W12t = W2t + 524288;         // 2*256*256 (k-major)
    float* invE   = (float*)(W12t + 131072);     // E
    float* invN   = invE + En;        // N
    float* pe_tab = invN + Nn;        // L*D
    float* bias12 = pe_tab + Ln * Dn; // 2*256
    float* bias2w = bias12 + 512;     // 2*256
    int* cnt_e  = (int*)(bias2w + 512);  // E
    int* cnt_n  = cnt_e + En;         // N
    int* cur_e  = cnt_n + Nn;         // E
    int* cur_n  = cur_e + En;         // N
    int* off_e  = cur_n + Nn;         // E+1
    int* off_n  = off_e + En + 1;     // N+1
    int* memb_e = off_n + Nn + 1;     // NNZ
    int* memb_n = memb_e + NNZn;      // NNZ
    float* outp = (float*)d_out;

    // 1. fused precompute (zero cnts | PE | W1t | W2t | W12 product)
    prep_kernel<<<3351, 256, 0, stream>>>(cnt_e, pe_tab, W1, W1t, W2, W2t,
                                          Wt, bt, Wi, bi, W12t, bias12, bias2w);
    // 2-4. CSR build
    count_deg_int<<<(NNZn + 255) / 256, 256, 0, stream>>>(node_idx, edge_idx, cnt_e, cnt_n, NNZn);
    scan_two<<<1, 256, 0, stream>>>(cnt_e, cnt_n, off_e, off_n, invE, invN);
    fill_csr<<<(NNZn + 255) / 256, 256, 0, stream>>>(node_idx, edge_idx, off_e, off_n,
                                                     cur_e, cur_n, memb_e, memb_n, NNZn);
    // 5. projections (text z=0, img z=1) -> packed bf16 xg (bias+PE fused)
    dim3 grdP(1, Nn / 64, 2);  // 300 blocks
    gemm_proj<<<grdP, 256, 0, stream>>>(text_table, img_table, rel, W1t, W2t, b1, b2,
                                        pe_tab, xg);
    // 6-7. first aggregation round: zg = A xg
    agg_kernel<<<En / 4, 256, 0, stream>>>(xg, eP, memb_e, off_e, invE, En);
    agg_kernel<<<Nn / 4, 256, 0, stream>>>(eP, zg, memb_n, off_n, invN, Nn);
    // 8. fused tail: per-b second agg round (rows b*Ln only) + conv + attention chain
    tail_all<<<Bn, 256, 0, stream>>>(zg, W12t, bias12, bias2w, off_e, memb_e, off_n, memb_n,
                                     invE, invN, user_table, uid, W3, b3, Wq, Wk, Wv, Wo,
                                     Wd, bd, W4, b4, outp);
}

// Round 6
// 383.474 us; speedup vs baseline: 4.2092x; 1.0851x over previous
//
#include <hip/hip_runtime.h>

typedef unsigned short u16;
typedef unsigned int u32;
typedef __bf16 bf16x8 __attribute__((ext_vector_type(8)));
typedef float f32x4 __attribute__((ext_vector_type(4)));

// Problem constants
constexpr int Bn = 32, Ln = 300, Dn = 256;
constexpr int Nn = Bn * Ln;          // 9600
constexpr int En = 4000, NNZn = 100000;
constexpr int DUn = 128, DFn = 384;
constexpr int PK = 512;              // packed row: [text 256 | img 256]
constexpr long NPl = (long)Nn * PK;  // 4915200
constexpr long EPl = (long)En * PK;  // 2048000
constexpr int PMAX = 1536;           // tail pair-list capacity

__device__ __forceinline__ u16 f2bf(float f) {
    union { float f; u32 u; } x{f};
    u32 u = x.u;
    u32 r = (u + 0x7FFFu + ((u >> 16) & 1u)) >> 16;
    return (u16)r;
}
__device__ __forceinline__ float bf2f(u16 s) {
    union { u32 u; float f; } x{(u32)s << 16};
    return x.f;
}

// ---------------- CSR build (no scan: bucket order is irrelevant) ----------------
__global__ void count_deg_int(const int* __restrict__ node_idx, const int* __restrict__ edge_idx,
                              int* __restrict__ cnt_e, int* __restrict__ cnt_n, int nnz) {
    int k = blockIdx.x * blockDim.x + threadIdx.x;
    if (k < nnz) {
        atomicAdd(&cnt_e[edge_idx[k]], 1);
        atomicAdd(&cnt_n[node_idx[k]], 1);
    }
}

// off[i] = atomicAdd(cursor, cnt[i]) gives disjoint (unordered) buckets — valid CSR.
__global__ void offs_kernel(const int* __restrict__ cnt_e, const int* __restrict__ cnt_n,
                            int* __restrict__ off_e, int* __restrict__ off_n,
                            float* __restrict__ invE, float* __restrict__ invN,
                            int* __restrict__ cursors) {
    int i = blockIdx.x * 256 + threadIdx.x;
    if (i < En) {
        int c = cnt_e[i];
        off_e[i] = atomicAdd(&cursors[0], c);
        invE[i] = 1.f / fmaxf((float)c, 1.f);
    }
    if (i < Nn) {
        int c = cnt_n[i];
        off_n[i] = atomicAdd(&cursors[1], c);
        invN[i] = 1.f / fmaxf((float)c, 1.f);
    }
}

__global__ void fill_csr(const int* __restrict__ node_idx, const int* __restrict__ edge_idx,
                         const int* __restrict__ off_e, const int* __restrict__ off_n,
                         int* __restrict__ cur_e, int* __restrict__ cur_n,
                         int* __restrict__ memb_e, int* __restrict__ memb_n, int nnz) {
    int k = blockIdx.x * blockDim.x + threadIdx.x;
    if (k < nnz) {
        int n = node_idx[k], ed = edge_idx[k];
        int pe = atomicAdd(&cur_e[ed], 1);
        memb_e[off_e[ed] + pe] = n;
        int pn = atomicAdd(&cur_n[n], 1);
        memb_n[off_n[n] + pn] = ed;
    }
}

// ---------------- fused precompute (block-ranged) ----------------
// blocks: [0,300) pe | [300,684) wT1 | [684,2732) wT2 | [2732,3244) wprod
__global__ __launch_bounds__(256) void prep_kernel(
    float* __restrict__ pe_tab,
    const float* __restrict__ W1, u16* __restrict__ W1t,
    const float* __restrict__ W2, u16* __restrict__ W2t,
    const float* __restrict__ Wt, const float* __restrict__ bt,
    const float* __restrict__ Wi, const float* __restrict__ bi,
    u16* __restrict__ W12t, float* __restrict__ bias12, float* __restrict__ bias2w) {
    int bid = blockIdx.x;
    int t = threadIdx.x;
    if (bid < 300) {
        int idx = bid * 256 + t;  // 76800 exact
        int l = idx / Dn, c = idx % Dn;
        float v = 0.f;
        if (l > 0) {
            int j2 = c >> 1;
            float div = expf(-0.07195578415606394f * (float)j2);
            float ang = (float)(l - 1) * div;
            v = 0.002f * ((c & 1) ? cosf(ang) : sinf(ang));
        }
        pe_tab[idx] = v;
        return;
    }
    bid -= 300;
    if (bid < 384) {
        int idx = bid * 256 + t;  // 98304 exact
        int k = idx >> 8, n = idx & 255;
        W1t[(size_t)n * 384 + k] = f2bf(W1[idx]);
        return;
    }
    bid -= 384;
    if (bid < 2048) {
        int idx = bid * 256 + t;  // 524288 exact
        int k = idx >> 8, n = idx & 255;
        W2t[(size_t)n * 2048 + k] = f2bf(W2[idx]);
        return;
    }
    bid -= 2048;
    {
        int idx = bid * 256 + t;  // 131072 exact
        int m = idx >> 16;
        int k = (idx >> 8) & 255;
        int n = idx & 255;
        const float* W0 = m ? Wi : Wt;
        const float* Wl1 = W0 + 65536;
        const float* b0 = m ? bi : bt;
        float acc = 0.f;
        for (int j = 0; j < 256; j++) acc += W0[k * 256 + j] * Wl1[j * 256 + n];
        // k-major layout for coalesced tail GEMV
        W12t[((size_t)m << 16) + k * 256 + n] = f2bf(acc);
        if (k == 0) {
            float ba = 0.f;
            for (int j = 0; j < 256; j++) ba += b0[j] * Wl1[j * 256 + n];
            bias12[m * 256 + n] = ba + b0[256 + n];
            bias2w[m * 256 + n] = b0[256 + n];
        }
    }
}

// ---------------- MFMA projection GEMM: BM=64, BN=256, BK=64, double-buffered ----
// grid.y in [0,300): y<150 -> img tile y (K=2048, long, dispatched first);
//                    y>=150 -> text tile y-150 (K=384, short, backfills)
#define LOFF(row, kc) (((row) << 6) + ((((kc) ^ ((row) & 7))) << 3))

__global__ __launch_bounds__(256) void gemm_proj(
    const float* __restrict__ T0, const float* __restrict__ T1,
    const int* __restrict__ rel,
    const u16* __restrict__ W1t, const u16* __restrict__ W2t,
    const float* __restrict__ b1, const float* __restrict__ b2,
    const float* __restrict__ pe_tab, u16* __restrict__ xg) {
    __shared__ u16 As[64 * 64];
    __shared__ u16 Bs[256 * 64];
    const int tid = threadIdx.x;
    const int lane = tid & 63;
    const int wv = tid >> 6;
    const int yy = blockIdx.y;
    const int z = (yy < 150) ? 1 : 0;
    const int m0 = ((yy < 150) ? yy : yy - 150) * 64;
    const int K = z ? 2048 : 384;
    const float* Af = z ? T1 : T0;
    const u16* Bt = z ? W2t : W1t;
    const float* bias = z ? b2 : b1;
    const int coloff = z ? 256 : 0;

    const int srow = tid >> 3;  // 0..31
    const int skc = tid & 7;    // 0..7
    long g0 = rel[m0 + srow];
    long g1 = rel[m0 + srow + 32];
    const float* ap0 = Af + g0 * (long)K + skc * 8;
    const float* ap1 = Af + g1 * (long)K + skc * 8;
    const u16* bp = Bt + (size_t)srow * K + skc * 8;

    f32x4 acc[4][4] = {};
    float4 ra0, ra1, rc0, rc1;
    uint4 rB[8];

    // prologue: load k0 = 0
    ra0 = *(const float4*)(ap0);
    ra1 = *(const float4*)(ap0 + 4);
    rc0 = *(const float4*)(ap1);
    rc1 = *(const float4*)(ap1 + 4);
#pragma unroll
    for (int it = 0; it < 8; it++) rB[it] = *(const uint4*)(bp + (size_t)(it * 32) * K);

    for (int k0 = 0; k0 < K; k0 += 64) {
        u16 ta[8] = {f2bf(ra0.x), f2bf(ra0.y), f2bf(ra0.z), f2bf(ra0.w),
                     f2bf(ra1.x), f2bf(ra1.y), f2bf(ra1.z), f2bf(ra1.w)};
        *(uint4*)&As[LOFF(srow, skc)] = *(uint4*)ta;
        u16 tb[8] = {f2bf(rc0.x), f2bf(rc0.y), f2bf(rc0.z), f2bf(rc0.w),
                     f2bf(rc1.x), f2bf(rc1.y), f2bf(rc1.z), f2bf(rc1.w)};
        *(uint4*)&As[LOFF(srow + 32, skc)] = *(uint4*)tb;
#pragma unroll
        for (int it = 0; it < 8; it++) *(uint4*)&Bs[LOFF(it * 32 + srow, skc)] = rB[it];
        __syncthreads();
        int kn = k0 + 64;
        if (kn < K) {  // prefetch next K-step into regs (overlaps MFMA below)
            ra0 = *(const float4*)(ap0 + kn);
            ra1 = *(const float4*)(ap0 + kn + 4);
            rc0 = *(const float4*)(ap1 + kn);
            rc1 = *(const float4*)(ap1 + kn + 4);
#pragma unroll
            for (int it = 0; it < 8; it++)
                rB[it] = *(const uint4*)(bp + (size_t)(it * 32) * K + kn);
        }
#pragma unroll
        for (int ks = 0; ks < 2; ks++) {
            int kc = ks * 4 + (lane >> 4);
            bf16x8 a[4], b[4];
#pragma unroll
            for (int mf = 0; mf < 4; mf++) a[mf] = *(bf16x8*)&As[LOFF(mf * 16 + (lane & 15), kc)];
#pragma unroll
            for (int nf = 0; nf < 4; nf++)
                b[nf] = *(bf16x8*)&Bs[LOFF(wv * 64 + nf * 16 + (lane & 15), kc)];
#pragma unroll
            for (int mf = 0; mf < 4; mf++)
#pragma unroll
                for (int nf = 0; nf < 4; nf++)
                    acc[mf][nf] = __builtin_amdgcn_mfma_f32_16x16x32_bf16(a[mf], b[nf], acc[mf][nf], 0, 0, 0);
        }
        __syncthreads();
    }

#pragma unroll
    for (int mf = 0; mf < 4; mf++) {
#pragma unroll
        for (int nf = 0; nf < 4; nf++) {
#pragma unroll
            for (int r = 0; r < 4; r++) {
                int row = m0 + mf * 16 + (lane >> 4) * 4 + r;
                int col = wv * 64 + nf * 16 + (lane & 15);
                float v = acc[mf][nf][r] + bias[col] + pe_tab[(row % Ln) * Dn + col];
                xg[(size_t)row * PK + coloff + col] = f2bf(v);
            }
        }
    }
}

// ---------------- packed aggregation (shfl-batched member indices) ----------------
__global__ __launch_bounds__(256) void agg_kernel(
    const u16* __restrict__ src, u16* __restrict__ dst,
    const int* __restrict__ memb, const int* __restrict__ off,
    const int* __restrict__ cnt, const float* __restrict__ inv, int nrows) {
    int row = blockIdx.x * 4 + (threadIdx.x >> 6);
    int lane = threadIdx.x & 63;
    if (row >= nrows) return;
    int s = off[row], tot = cnt[row];
    float acc[8] = {};
    const u16* base = src + (size_t)lane * 8;
    for (int cb = 0; cb < tot; cb += 64) {
        int m = min(64, tot - cb);
        int my = (lane < m) ? memb[s + cb + lane] : 0;
        for (int j = 0; j < m; j++) {
            int r = __builtin_amdgcn_readfirstlane(__shfl(my, j));
            uint4 v = *(const uint4*)(base + (size_t)r * PK);
            u16 h[8];
            *(uint4*)h = v;
#pragma unroll
            for (int q = 0; q < 8; q++) acc[q] += bf2f(h[q]);
        }
    }
    float sc = inv[row];
    u16 o[8];
#pragma unroll
    for (int j = 0; j < 8; j++) o[j] = f2bf(acc[j] * sc);
    *(uint4*)(dst + (size_t)row * PK + lane * 8) = *(uint4*)o;
}

// ---------------- fused tail: per-b agg3+agg4 + conv GEMV + KV + F/Q/K/V + attn + out ----
__global__ __launch_bounds__(256) void tail_all(
    const u16* __restrict__ zg, const u16* __restrict__ W12t,
    const float* __restrict__ bias12, const float* __restrict__ bias2w,
    const int* __restrict__ off_e, const int* __restrict__ cnt_e, const int* __restrict__ memb_e,
    const int* __restrict__ off_n, const int* __restrict__ cnt_n, const int* __restrict__ memb_n,
    const float* __restrict__ invE, const float* __restrict__ invN,
    const float* __restrict__ ut, const int* __restrict__ uid,
    const float* __restrict__ W3, const float* __restrict__ b3,
    const float* __restrict__ Wq, const float* __restrict__ Wk,
    const float* __restrict__ Wv, const float* __restrict__ Wo,
    const float* __restrict__ Wd, const float* __restrict__ bd,
    const float* __restrict__ W4, const float* __restrict__ b4,
    float* __restrict__ out) {
    __shared__ float zrow[PK];
    __shared__ float kv0[DFn], kv1[DFn], Fv[DFn], qv[DFn];
    __shared__ float K0[DFn], K1[DFn], V0[DFn], V1[DFn], ov[DFn], o2[DFn];
    __shared__ int plist[PMAX];
    __shared__ float pw[PMAX];
    __shared__ float sarr[8], wgt[8], red[4];
    __shared__ int pcount;

    int b = blockIdx.x, t = threadIdx.x;
    int r = b * Ln;
    int ns = off_n[r], ne = cnt_n[r];

    // wave 0 builds flat (node, weight) pair list for the two-hop mean
    if (t < 64) {
        int e = (t < ne) ? memb_n[ns + t] : 0;
        int es = (t < ne) ? off_e[e] : 0;
        int em = (t < ne) ? cnt_e[e] : 0;
        float w = (t < ne) ? invE[e] : 0.f;
        int pos = em;
#pragma unroll
        for (int o = 1; o < 64; o <<= 1) {
            int x = __shfl_up(pos, o);
            if (t >= o) pos += x;
        }
        int total = __shfl(pos, 63);
        pos -= em;  // exclusive prefix
        for (int j = 0; j < em; j++) {
            if (pos + j < PMAX) {
                plist[pos + j] = memb_e[es + j];
                pw[pos + j] = w;
            }
        }
        if (t == 0) pcount = min(total, PMAX);
    }
    __syncthreads();
    int P = pcount;

    // zrow = invN * sum_pairs w * zg[n]  (thread t covers cols 2t, 2t+1)
    {
        float za0 = 0.f, za1 = 0.f;
#pragma unroll 4
        for (int i = 0; i < P; i++) {
            int n = plist[i];
            float w = pw[i];
            u32 v = *(const u32*)&zg[(size_t)n * PK + 2 * t];
            za0 += bf2f((u16)(v & 0xffff)) * w;
            za1 += bf2f((u16)(v >> 16)) * w;
        }
        float sN = invN[r];
        zrow[2 * t] = za0 * sN;
        zrow[2 * t + 1] = za1 * sN;
    }
    __syncthreads();

    // conv GEMV: kv[c] = zrow[m] @ W12[m] + bias12 (deg0 -> bias2w); user part
    for (int c = t; c < 512; c += 256) {
        int m = c >> 8, cc = c & 255;
        float acc;
        if (ne == 0) {
            acc = bias2w[c];
        } else {
            acc = bias12[c];
            const u16* wp = W12t + ((size_t)m << 16) + cc;
            for (int k = 0; k < 256; k++) acc += zrow[m * 256 + k] * bf2f(wp[(size_t)k * 256]);
        }
        if (m == 0) kv0[cc] = acc;
        else kv1[cc] = acc;
    }
    if (t < 128) {
        float u = ut[(size_t)uid[b] * DUn + t];
        kv0[256 + t] = u;
        kv1[256 + t] = u;
    }
    __syncthreads();

    // F = [kv0 kv1] @ W3 + b3
    for (int c = t; c < DFn; c += 256) {
        float acc = b3[c];
        for (int k = 0; k < DFn; k++) acc += kv0[k] * W3[(size_t)k * DFn + c];
        for (int k = 0; k < DFn; k++) acc += kv1[k] * W3[(size_t)(DFn + k) * DFn + c];
        Fv[c] = acc;
    }
    __syncthreads();

    // Q, K0, K1, V0, V1
    for (int c = t; c < DFn; c += 256) {
        float aq = 0.f, ak0 = 0.f, ak1 = 0.f, av0 = 0.f, av1 = 0.f;
        for (int k = 0; k < DFn; k++) {
            float wk = Wk[(size_t)k * DFn + c];
            float wvv = Wv[(size_t)k * DFn + c];
            aq += Fv[k] * Wq[(size_t)k * DFn + c];
            ak0 += kv0[k] * wk;
            ak1 += kv1[k] * wk;
            av0 += kv0[k] * wvv;
            av1 += kv1[k] * wvv;
        }
        qv[c] = aq;
        K0[c] = ak0;
        K1[c] = ak1;
        V0[c] = av0;
        V1[c] = av1;
    }
    __syncthreads();

    // scores: 8 groups of 32 lanes, group g = (head h = g>>1, kv wch = g&1)
    {
        int g = t >> 5, l = t & 31;
        int h = g >> 1, wch = g & 1;
        const float* Kp = (wch ? K1 : K0) + h * 96;
        const float* qp = qv + h * 96;
        float p = 0.f;
        for (int d = l; d < 96; d += 32) p += qp[d] * Kp[d];
#pragma unroll
        for (int o = 16; o; o >>= 1) p += __shfl_down(p, o, 32);
        if (l == 0) sarr[g] = p * 0.10206207261596575f;  // 1/sqrt(96)
    }
    __syncthreads();
    if (t < 4) {
        float s0 = sarr[2 * t], s1 = sarr[2 * t + 1];
        float m = fmaxf(s0, s1);
        float e0 = expf(s0 - m), e1 = expf(s1 - m);
        float inv = 1.f / (e0 + e1);
        wgt[2 * t] = e0 * inv;
        wgt[2 * t + 1] = e1 * inv;
    }
    __syncthreads();
    for (int c = t; c < DFn; c += 256) {
        int h = c / 96;
        ov[c] = wgt[2 * h] * V0[c] + wgt[2 * h + 1] * V1[c];
    }
    __syncthreads();
    // o2 = ov @ Wo + F (residual is pre-Wq fused)
    for (int c = t; c < DFn; c += 256) {
        float acc = Fv[c];
        for (int k = 0; k < DFn; k++) acc += ov[k] * Wo[(size_t)k * DFn + c];
        o2[c] = acc;
    }
    __syncthreads();
    // o3 = relu(o2 @ Wd + bd) -> reuse qv
    for (int c = t; c < DFn; c += 256) {
        float acc = bd[c];
        for (int k = 0; k < DFn; k++) acc += o2[k] * Wd[(size_t)k * DFn + c];
        qv[c] = fmaxf(acc, 0.f);
    }
    __syncthreads();
    float p2 = 0.f;
    for (int c = t; c < DFn; c += 256) p2 += qv[c] * W4[c];
#pragma unroll
    for (int o = 32; o; o >>= 1) p2 += __shfl_down(p2, o);
    if ((t & 63) == 0) red[t >> 6] = p2;
    __syncthreads();
    if (t == 0) out[b] = red[0] + red[1] + red[2] + red[3] + b4[0];
}

// ---------------- launch ----------------
extern "C" void kernel_launch(void* const* d_in, const int* in_sizes, int n_in,
                              void* d_out, int out_size, void* d_ws, size_t ws_size,
                              hipStream_t stream) {
    const float* text_table = (const float*)d_in[2];
    const float* img_table  = (const float*)d_in[3];
    const float* W1 = (const float*)d_in[4];
    const float* b1 = (const float*)d_in[5];
    const float* W2 = (const float*)d_in[6];
    const float* b2 = (const float*)d_in[7];
    const float* user_table = (const float*)d_in[8];
    const float* Wt = (const float*)d_in[9];
    const float* bt = (const float*)d_in[10];
    const float* Wi = (const float*)d_in[11];
    const float* bi = (const float*)d_in[12];
    const float* Wq = (const float*)d_in[13];
    const float* Wk = (const float*)d_in[14];
    const float* Wv = (const float*)d_in[15];
    const float* Wo = (const float*)d_in[16];
    const float* W3 = (const float*)d_in[17];
    const float* b3 = (const float*)d_in[18];
    const float* Wd = (const float*)d_in[19];
    const float* bd = (const float*)d_in[20];
    const float* W4 = (const float*)d_in[21];
    const float* b4 = (const float*)d_in[22];
    const int* rel = (const int*)d_in[23];
    const int* uid = (const int*)d_in[24];
    const int* hg  = (const int*)d_in[25];
    const int* node_idx = hg;
    const int* edge_idx = hg + NNZn;

    // ---- workspace layout ----
    u16* xg  = (u16*)d_ws;            // N*PK packed [t|i]
    u16* eP  = xg + NPl;              // E*PK
    u16* zg  = eP + EPl;              // N*PK
    u16* W1t = zg + NPl;              // 256*384
    u16* W2t = W1t + 98304;           // 256*2048
    u16* W12t = W2t + 524288;         // 2*256*256 (k-major)
    float* invE   = (float*)(W12t + 131072);     // E
    float* invN   = invE + En;        // N
    float* pe_tab = invN + Nn;        // L*D
    float* bias12 = pe_tab + Ln * Dn; // 2*256
    float* bias2w = bias12 + 512;     // 2*256
    int* cnt_e  = (int*)(bias2w + 512);  // E      -- zeroed region start
    int* cnt_n  = cnt_e + En;         // N
    int* cur_e  = cnt_n + Nn;         // E
    int* cur_n  = cur_e + En;         // N
    int* cursors = cur_n + Nn;        // 2        -- zeroed region end
    int* off_e  = cursors + 2;        // E
    int* off_n  = off_e + En;         // N
    int* memb_e = off_n + Nn;         // NNZ
    int* memb_n = memb_e + NNZn;      // NNZ
    float* outp = (float*)d_out;

    // 0. zero counters/cursors (async memset is graph-capture safe)
    hipMemsetAsync(cnt_e, 0, (size_t)(2 * (En + Nn) + 2) * sizeof(int), stream);
    // 1. fused precompute (PE | W1t | W2t | W12 product)
    prep_kernel<<<3244, 256, 0, stream>>>(pe_tab, W1, W1t, W2, W2t,
                                          Wt, bt, Wi, bi, W12t, bias12, bias2w);
    // 2-4. CSR build (unordered buckets; no scan)
    count_deg_int<<<(NNZn + 255) / 256, 256, 0, stream>>>(node_idx, edge_idx, cnt_e, cnt_n, NNZn);
    offs_kernel<<<(Nn + 255) / 256, 256, 0, stream>>>(cnt_e, cnt_n, off_e, off_n, invE, invN, cursors);
    fill_csr<<<(NNZn + 255) / 256, 256, 0, stream>>>(node_idx, edge_idx, off_e, off_n,
                                                     cur_e, cur_n, memb_e, memb_n, NNZn);
    // 5. projections (img tiles first for LPT) -> packed bf16 xg (bias+PE fused)
    dim3 grdP(1, 300, 1);
    gemm_proj<<<grdP, 256, 0, stream>>>(text_table, img_table, rel, W1t, W2t, b1, b2,
                                        pe_tab, xg);
    // 6-7. first aggregation round: zg = A xg
    agg_kernel<<<En / 4, 256, 0, stream>>>(xg, eP, memb_e, off_e, cnt_e, invE, En);
    agg_kernel<<<Nn / 4, 256, 0, stream>>>(eP, zg, memb_n, off_n, cnt_n, invN, Nn);
    // 8. fused tail: per-b second agg round (rows b*Ln only) + conv + attention chain
    tail_all<<<Bn, 256, 0, stream>>>(zg, W12t, bias12, bias2w, off_e, cnt_e, memb_e,
                                     off_n, cnt_n, memb_n, invE, invN, user_table, uid,
                                     W3, b3, Wq, Wk, Wv, Wo, Wd, bd, W4, b4, outp);
}

// Round 7
// 321.459 us; speedup vs baseline: 5.0212x; 1.1929x over previous
//
#include <hip/hip_runtime.h>

typedef unsigned short u16;
typedef unsigned int u32;
typedef __bf16 bf16x8 __attribute__((ext_vector_type(8)));
typedef float f32x4 __attribute__((ext_vector_type(4)));

// Problem constants
constexpr int Bn = 32, Ln = 300, Dn = 256;
constexpr int Nn = Bn * Ln;          // 9600
constexpr int En = 4000, NNZn = 100000;
constexpr int DUn = 128, DFn = 384;
constexpr int PK = 512;              // packed row: [text 256 | img 256]
constexpr long NPl = (long)Nn * PK;  // 4915200
constexpr long EPl = (long)En * PK;  // 2048000
constexpr int PMAX = 1536;           // tail pair-list capacity

// prep_all block-segment offsets
constexpr int SEG_WPROD = 0;                  // 512 blocks
constexpr int SEG_GIMG = SEG_WPROD + 512;     // 9600 blocks
constexpr int SEG_W2T  = SEG_GIMG + 9600;     // 2048 blocks
constexpr int SEG_GTXT = SEG_W2T + 2048;      // 2400 blocks
constexpr int SEG_W1T  = SEG_GTXT + 2400;     // 384 blocks
constexpr int SEG_PE   = SEG_W1T + 384;       // 300 blocks
constexpr int SEG_CNT  = SEG_PE + 300;        // 391 blocks
constexpr int SEG_END  = SEG_CNT + 391;       // 15635

__device__ __forceinline__ u16 f2bf(float f) {
    union { float f; u32 u; } x{f};
    u32 u = x.u;
    u32 r = (u + 0x7FFFu + ((u >> 16) & 1u)) >> 16;
    return (u16)r;
}
__device__ __forceinline__ float bf2f(u16 s) {
    union { u32 u; float f; } x{(u32)s << 16};
    return x.f;
}

// ---------------- fused prologue: all independent precompute ----------------
__global__ __launch_bounds__(256) void prep_all(
    float* __restrict__ pe_tab,
    const float* __restrict__ W1, u16* __restrict__ W1t,
    const float* __restrict__ W2, u16* __restrict__ W2t,
    const float* __restrict__ Wt, const float* __restrict__ bt,
    const float* __restrict__ Wi, const float* __restrict__ bi,
    u16* __restrict__ W12t, float* __restrict__ bias12, float* __restrict__ bias2w,
    const int* __restrict__ node_idx, const int* __restrict__ edge_idx,
    int* __restrict__ cnt_e, int* __restrict__ cnt_n,
    const float* __restrict__ text_table, const float* __restrict__ img_table,
    const int* __restrict__ rel, u16* __restrict__ Atx, u16* __restrict__ Aim) {
    int bid = blockIdx.x;
    int t = threadIdx.x;
    if (bid < SEG_GIMG) {  // wprod: W12 = W0 @ W1 (per modality), k-major out
        int idx = bid * 256 + t;  // 131072
        int m = idx >> 16;
        int k = (idx >> 8) & 255;
        int n = idx & 255;
        const float* W0 = m ? Wi : Wt;
        const float* Wl1 = W0 + 65536;
        const float* b0 = m ? bi : bt;
        float acc = 0.f;
        for (int j = 0; j < 256; j++) acc += W0[k * 256 + j] * Wl1[j * 256 + n];
        W12t[((size_t)m << 16) + k * 256 + n] = f2bf(acc);
        if (k == 0) {
            float ba = 0.f;
            for (int j = 0; j < 256; j++) ba += b0[j] * Wl1[j * 256 + n];
            bias12[m * 256 + n] = ba + b0[256 + n];
            bias2w[m * 256 + n] = b0[256 + n];
        }
        return;
    }
    if (bid < SEG_W2T) {  // gather img row -> packed bf16 (streaming memcpy)
        int r = bid - SEG_GIMG;
        const float4* s4 = (const float4*)(img_table + (size_t)rel[r] * 2048);
        u16* drow = Aim + (size_t)r * 2048;
#pragma unroll
        for (int i = 0; i < 2; i++) {
            int e = i * 256 + t;  // 512 float4 per row
            float4 v = s4[e];
            u16 o[4] = {f2bf(v.x), f2bf(v.y), f2bf(v.z), f2bf(v.w)};
            *(uint2*)&drow[e * 4] = *(uint2*)o;
        }
        return;
    }
    if (bid < SEG_GTXT) {  // W2 transpose+convert
        int idx = (bid - SEG_W2T) * 256 + t;  // 524288
        int k = idx >> 8, n = idx & 255;
        W2t[(size_t)n * 2048 + k] = f2bf(W2[idx]);
        return;
    }
    if (bid < SEG_W1T) {  // gather text rows (4 per block)
        int base = (bid - SEG_GTXT) * 4;
#pragma unroll
        for (int i0 = 0; i0 < 2; i0++) {
            int i = i0 * 256 + t;  // 4 rows x 96 float4 = 384
            if (i < 384) {
                int rr = i / 96, c4 = i % 96;
                int r = base + rr;
                const float4* s4 = (const float4*)(text_table + (size_t)rel[r] * 384);
                float4 v = s4[c4];
                u16 o[4] = {f2bf(v.x), f2bf(v.y), f2bf(v.z), f2bf(v.w)};
                *(uint2*)&Atx[(size_t)r * 384 + c4 * 4] = *(uint2*)o;
            }
        }
        return;
    }
    if (bid < SEG_PE) {  // W1 transpose+convert
        int idx = (bid - SEG_W1T) * 256 + t;  // 98304
        int k = idx >> 8, n = idx & 255;
        W1t[(size_t)n * 384 + k] = f2bf(W1[idx]);
        return;
    }
    if (bid < SEG_CNT) {  // PE table
        int idx = (bid - SEG_PE) * 256 + t;  // 76800
        int l = idx / Dn, c = idx % Dn;
        float v = 0.f;
        if (l > 0) {
            int j2 = c >> 1;
            float div = expf(-0.07195578415606394f * (float)j2);
            float ang = (float)(l - 1) * div;
            v = 0.002f * ((c & 1) ? cosf(ang) : sinf(ang));
        }
        pe_tab[idx] = v;
        return;
    }
    {  // degree count
        int k = (bid - SEG_CNT) * 256 + t;
        if (k < NNZn) {
            atomicAdd(&cnt_e[edge_idx[k]], 1);
            atomicAdd(&cnt_n[node_idx[k]], 1);
        }
    }
}

// ---------------- CSR build (unordered buckets; no scan) ----------------
__global__ void offs_kernel(const int* __restrict__ cnt_e, const int* __restrict__ cnt_n,
                            int* __restrict__ off_e, int* __restrict__ off_n,
                            float* __restrict__ invE, float* __restrict__ invN,
                            int* __restrict__ cursors) {
    int i = blockIdx.x * 256 + threadIdx.x;
    if (i < En) {
        int c = cnt_e[i];
        off_e[i] = atomicAdd(&cursors[0], c);
        invE[i] = 1.f / fmaxf((float)c, 1.f);
    }
    if (i < Nn) {
        int c = cnt_n[i];
        off_n[i] = atomicAdd(&cursors[1], c);
        invN[i] = 1.f / fmaxf((float)c, 1.f);
    }
}

__global__ void fill_csr(const int* __restrict__ node_idx, const int* __restrict__ edge_idx,
                         const int* __restrict__ off_e, const int* __restrict__ off_n,
                         int* __restrict__ cur_e, int* __restrict__ cur_n,
                         int* __restrict__ memb_e, int* __restrict__ memb_n, int nnz) {
    int k = blockIdx.x * blockDim.x + threadIdx.x;
    if (k < nnz) {
        int n = node_idx[k], ed = edge_idx[k];
        int pe = atomicAdd(&cur_e[ed], 1);
        memb_e[off_e[ed] + pe] = n;
        int pn = atomicAdd(&cur_n[n], 1);
        memb_n[off_n[n] + pn] = ed;
    }
}

// ---------------- MFMA projection GEMM: BM=64, BN=256, BK=64, double-buffered ----
// A is pre-gathered packed bf16 (Atx / Aim). grid.y: y<150 -> img tile (K=2048,
// long, dispatched first for LPT); y>=150 -> text tile y-150 (K=384).
#define LOFF(row, kc) (((row) << 6) + ((((kc) ^ ((row) & 7))) << 3))

__global__ __launch_bounds__(256) void gemm_proj(
    const u16* __restrict__ Atx, const u16* __restrict__ Aim,
    const u16* __restrict__ W1t, const u16* __restrict__ W2t,
    const float* __restrict__ b1, const float* __restrict__ b2,
    const float* __restrict__ pe_tab, u16* __restrict__ xg) {
    __shared__ u16 As[64 * 64];
    __shared__ u16 Bs[256 * 64];
    const int tid = threadIdx.x;
    const int lane = tid & 63;
    const int wv = tid >> 6;
    const int yy = blockIdx.y;
    const int z = (yy < 150) ? 1 : 0;
    const int m0 = ((yy < 150) ? yy : yy - 150) * 64;
    const int K = z ? 2048 : 384;
    const u16* A = z ? Aim : Atx;
    const u16* Bt = z ? W2t : W1t;
    const float* bias = z ? b2 : b1;
    const int coloff = z ? 256 : 0;

    const int srow = tid >> 3;  // 0..31
    const int skc = tid & 7;    // 0..7
    const u16* ap0 = A + (size_t)(m0 + srow) * K + skc * 8;
    const u16* ap1 = A + (size_t)(m0 + srow + 32) * K + skc * 8;
    const u16* bp = Bt + (size_t)srow * K + skc * 8;

    f32x4 acc[4][4] = {};
    uint4 rA0, rA1, rB[8];

    rA0 = *(const uint4*)(ap0);
    rA1 = *(const uint4*)(ap1);
#pragma unroll
    for (int it = 0; it < 8; it++) rB[it] = *(const uint4*)(bp + (size_t)(it * 32) * K);

    for (int k0 = 0; k0 < K; k0 += 64) {
        *(uint4*)&As[LOFF(srow, skc)] = rA0;
        *(uint4*)&As[LOFF(srow + 32, skc)] = rA1;
#pragma unroll
        for (int it = 0; it < 8; it++) *(uint4*)&Bs[LOFF(it * 32 + srow, skc)] = rB[it];
        __syncthreads();
        int kn = k0 + 64;
        if (kn < K) {  // prefetch next K-step into regs (overlaps MFMA below)
            rA0 = *(const uint4*)(ap0 + kn);
            rA1 = *(const uint4*)(ap1 + kn);
#pragma unroll
            for (int it = 0; it < 8; it++)
                rB[it] = *(const uint4*)(bp + (size_t)(it * 32) * K + kn);
        }
#pragma unroll
        for (int ks = 0; ks < 2; ks++) {
            int kc = ks * 4 + (lane >> 4);
            bf16x8 a[4], b[4];
#pragma unroll
            for (int mf = 0; mf < 4; mf++) a[mf] = *(bf16x8*)&As[LOFF(mf * 16 + (lane & 15), kc)];
#pragma unroll
            for (int nf = 0; nf < 4; nf++)
                b[nf] = *(bf16x8*)&Bs[LOFF(wv * 64 + nf * 16 + (lane & 15), kc)];
#pragma unroll
            for (int mf = 0; mf < 4; mf++)
#pragma unroll
                for (int nf = 0; nf < 4; nf++)
                    acc[mf][nf] = __builtin_amdgcn_mfma_f32_16x16x32_bf16(a[mf], b[nf], acc[mf][nf], 0, 0, 0);
        }
        __syncthreads();
    }

#pragma unroll
    for (int mf = 0; mf < 4; mf++) {
#pragma unroll
        for (int nf = 0; nf < 4; nf++) {
#pragma unroll
            for (int r = 0; r < 4; r++) {
                int row = m0 + mf * 16 + (lane >> 4) * 4 + r;
                int col = wv * 64 + nf * 16 + (lane & 15);
                float v = acc[mf][nf][r] + bias[col] + pe_tab[(row % Ln) * Dn + col];
                xg[(size_t)row * PK + coloff + col] = f2bf(v);
            }
        }
    }
}

// ---------------- packed aggregation (shfl-batched member indices) ----------------
__global__ __launch_bounds__(256) void agg_kernel(
    const u16* __restrict__ src, u16* __restrict__ dst,
    const int* __restrict__ memb, const int* __restrict__ off,
    const int* __restrict__ cnt, const float* __restrict__ inv, int nrows) {
    int row = blockIdx.x * 4 + (threadIdx.x >> 6);
    int lane = threadIdx.x & 63;
    if (row >= nrows) return;
    int s = off[row], tot = cnt[row];
    float acc[8] = {};
    const u16* base = src + (size_t)lane * 8;
    for (int cb = 0; cb < tot; cb += 64) {
        int m = min(64, tot - cb);
        int my = (lane < m) ? memb[s + cb + lane] : 0;
        for (int j = 0; j < m; j++) {
            int r = __builtin_amdgcn_readfirstlane(__shfl(my, j));
            uint4 v = *(const uint4*)(base + (size_t)r * PK);
            u16 h[8];
            *(uint4*)h = v;
#pragma unroll
            for (int q = 0; q < 8; q++) acc[q] += bf2f(h[q]);
        }
    }
    float sc = inv[row];
    u16 o[8];
#pragma unroll
    for (int j = 0; j < 8; j++) o[j] = f2bf(acc[j] * sc);
    *(uint4*)(dst + (size_t)row * PK + lane * 8) = *(uint4*)o;
}

// ---------------- fused tail (384 threads: one column per thread) ----------------
__global__ __launch_bounds__(384) void tail_all(
    const u16* __restrict__ zg, const u16* __restrict__ W12t,
    const float* __restrict__ bias12, const float* __restrict__ bias2w,
    const int* __restrict__ off_e, const int* __restrict__ cnt_e, const int* __restrict__ memb_e,
    const int* __restrict__ off_n, const int* __restrict__ cnt_n, const int* __restrict__ memb_n,
    const float* __restrict__ invE, const float* __restrict__ invN,
    const float* __restrict__ ut, const int* __restrict__ uid,
    const float* __restrict__ W3, const float* __restrict__ b3,
    const float* __restrict__ Wq, const float* __restrict__ Wk,
    const float* __restrict__ Wv, const float* __restrict__ Wo,
    const float* __restrict__ Wd, const float* __restrict__ bd,
    const float* __restrict__ W4, const float* __restrict__ b4,
    float* __restrict__ out) {
    __shared__ float zrow[PK];
    __shared__ float kv0[DFn], kv1[DFn], Fv[DFn], qv[DFn];
    __shared__ float K0[DFn], K1[DFn], V0[DFn], V1[DFn], ov[DFn], o2[DFn];
    __shared__ int plist[PMAX];
    __shared__ float pw[PMAX];
    __shared__ float sarr[8], wgt[8], red[6];
    __shared__ int pcount;

    int b = blockIdx.x, t = threadIdx.x;
    int r = b * Ln;
    int ns = off_n[r], ne = cnt_n[r];

    // wave 0 builds flat (node, weight) pair list for the two-hop mean
    if (t < 64) {
        int e = (t < ne) ? memb_n[ns + t] : 0;
        int es = (t < ne) ? off_e[e] : 0;
        int em = (t < ne) ? cnt_e[e] : 0;
        float w = (t < ne) ? invE[e] : 0.f;
        int pos = em;
#pragma unroll
        for (int o = 1; o < 64; o <<= 1) {
            int x = __shfl_up(pos, o);
            if (t >= o) pos += x;
        }
        int total = __shfl(pos, 63);
        pos -= em;  // exclusive prefix
        for (int j = 0; j < em; j++) {
            if (pos + j < PMAX) {
                plist[pos + j] = memb_e[es + j];
                pw[pos + j] = w;
            }
        }
        if (t == 0) pcount = min(total, PMAX);
    }
    __syncthreads();
    int P = pcount;

    // zrow = invN * sum_pairs w * zg[n]  (threads 0..255: cols 2t, 2t+1)
    if (t < 256) {
        float za0 = 0.f, za1 = 0.f;
#pragma unroll 4
        for (int i = 0; i < P; i++) {
            int n = plist[i];
            float w = pw[i];
            u32 v = *(const u32*)&zg[(size_t)n * PK + 2 * t];
            za0 += bf2f((u16)(v & 0xffff)) * w;
            za1 += bf2f((u16)(v >> 16)) * w;
        }
        float sN = invN[r];
        zrow[2 * t] = za0 * sN;
        zrow[2 * t + 1] = za1 * sN;
    }
    __syncthreads();

    // conv GEMV: kv[c] = zrow[m] @ W12[m] + bias12 (deg0 -> bias2w); user part
    for (int c = t; c < 512; c += 384) {
        int m = c >> 8, cc = c & 255;
        float acc;
        if (ne == 0) {
            acc = bias2w[c];
        } else {
            acc = bias12[c];
            const u16* wp = W12t + ((size_t)m << 16) + cc;
            for (int k = 0; k < 256; k++) acc += zrow[m * 256 + k] * bf2f(wp[(size_t)k * 256]);
        }
        if (m == 0) kv0[cc] = acc;
        else kv1[cc] = acc;
    }
    if (t < 128) {
        float u = ut[(size_t)uid[b] * DUn + t];
        kv0[256 + t] = u;
        kv1[256 + t] = u;
    }
    __syncthreads();

    // F = [kv0 kv1] @ W3 + b3   (one column per thread)
    {
        int c = t;
        float acc = b3[c];
        for (int k = 0; k < DFn; k++) acc += kv0[k] * W3[(size_t)k * DFn + c];
        for (int k = 0; k < DFn; k++) acc += kv1[k] * W3[(size_t)(DFn + k) * DFn + c];
        Fv[c] = acc;
    }
    __syncthreads();

    // Q, K0, K1, V0, V1 (one column per thread)
    {
        int c = t;
        float aq = 0.f, ak0 = 0.f, ak1 = 0.f, av0 = 0.f, av1 = 0.f;
        for (int k = 0; k < DFn; k++) {
            float wk = Wk[(size_t)k * DFn + c];
            float wvv = Wv[(size_t)k * DFn + c];
            aq += Fv[k] * Wq[(size_t)k * DFn + c];
            ak0 += kv0[k] * wk;
            ak1 += kv1[k] * wk;
            av0 += kv0[k] * wvv;
            av1 += kv1[k] * wvv;
        }
        qv[c] = aq;
        K0[c] = ak0;
        K1[c] = ak1;
        V0[c] = av0;
        V1[c] = av1;
    }
    __syncthreads();

    // scores: 8 groups of 32 lanes (t<256), group g = (head g>>1, kv g&1)
    if (t < 256) {
        int g = t >> 5, l = t & 31;
        int h = g >> 1, wch = g & 1;
        const float* Kp = (wch ? K1 : K0) + h * 96;
        const float* qp = qv + h * 96;
        float p = 0.f;
        for (int d = l; d < 96; d += 32) p += qp[d] * Kp[d];
#pragma unroll
        for (int o = 16; o; o >>= 1) p += __shfl_down(p, o, 32);
        if (l == 0) sarr[g] = p * 0.10206207261596575f;  // 1/sqrt(96)
    }
    __syncthreads();
    if (t < 4) {
        float s0 = sarr[2 * t], s1 = sarr[2 * t + 1];
        float m = fmaxf(s0, s1);
        float e0 = expf(s0 - m), e1 = expf(s1 - m);
        float inv = 1.f / (e0 + e1);
        wgt[2 * t] = e0 * inv;
        wgt[2 * t + 1] = e1 * inv;
    }
    __syncthreads();
    {
        int c = t;
        int h = c / 96;
        ov[c] = wgt[2 * h] * V0[c] + wgt[2 * h + 1] * V1[c];
    }
    __syncthreads();
    // o2 = ov @ Wo + F (residual is pre-Wq fused)
    {
        int c = t;
        float acc = Fv[c];
        for (int k = 0; k < DFn; k++) acc += ov[k] * Wo[(size_t)k * DFn + c];
        o2[c] = acc;
    }
    __syncthreads();
    // o3 = relu(o2 @ Wd + bd) -> reuse qv
    {
        int c = t;
        float acc = bd[c];
        for (int k = 0; k < DFn; k++) acc += o2[k] * Wd[(size_t)k * DFn + c];
        qv[c] = fmaxf(acc, 0.f);
    }
    __syncthreads();
    float p2 = qv[t] * W4[t];
#pragma unroll
    for (int o = 32; o; o >>= 1) p2 += __shfl_down(p2, o);
    if ((t & 63) == 0) red[t >> 6] = p2;
    __syncthreads();
    if (t == 0)
        out[b] = red[0] + red[1] + red[2] + red[3] + red[4] + red[5] + b4[0];
}

// ---------------- launch ----------------
extern "C" void kernel_launch(void* const* d_in, const int* in_sizes, int n_in,
                              void* d_out, int out_size, void* d_ws, size_t ws_size,
                              hipStream_t stream) {
    const float* text_table = (const float*)d_in[2];
    const float* img_table  = (const float*)d_in[3];
    const float* W1 = (const float*)d_in[4];
    const float* b1 = (const float*)d_in[5];
    const float* W2 = (const float*)d_in[6];
    const float* b2 = (const float*)d_in[7];
    const float* user_table = (const float*)d_in[8];
    const float* Wt = (const float*)d_in[9];
    const float* bt = (const float*)d_in[10];
    const float* Wi = (const float*)d_in[11];
    const float* bi = (const float*)d_in[12];
    const float* Wq = (const float*)d_in[13];
    const float* Wk = (const float*)d_in[14];
    const float* Wv = (const float*)d_in[15];
    const float* Wo = (const float*)d_in[16];
    const float* W3 = (const float*)d_in[17];
    const float* b3 = (const float*)d_in[18];
    const float* Wd = (const float*)d_in[19];
    const float* bd = (const float*)d_in[20];
    const float* W4 = (const float*)d_in[21];
    const float* b4 = (const float*)d_in[22];
    const int* rel = (const int*)d_in[23];
    const int* uid = (const int*)d_in[24];
    const int* hg  = (const int*)d_in[25];
    const int* node_idx = hg;
    const int* edge_idx = hg + NNZn;

    // ---- workspace layout ----
    u16* xg  = (u16*)d_ws;            // N*PK packed [t|i]
    u16* eP  = xg + NPl;              // E*PK
    u16* zg  = eP + EPl;              // N*PK
    u16* Atx = zg + NPl;              // N*384 packed gathered text (bf16)
    u16* Aim = Atx + (size_t)Nn * 384;  // N*2048 packed gathered img (bf16)
    u16* W1t = Aim + (size_t)Nn * 2048; // 256*384
    u16* W2t = W1t + 98304;           // 256*2048
    u16* W12t = W2t + 524288;         // 2*256*256 (k-major)
    float* invE   = (float*)(W12t + 131072);     // E
    float* invN   = invE + En;        // N
    float* pe_tab = invN + Nn;        // L*D
    float* bias12 = pe_tab + Ln * Dn; // 2*256
    float* bias2w = bias12 + 512;     // 2*256
    int* cnt_e  = (int*)(bias2w + 512);  // E      -- zeroed region start
    int* cnt_n  = cnt_e + En;         // N
    int* cur_e  = cnt_n + Nn;         // E
    int* cur_n  = cur_e + En;         // N
    int* cursors = cur_n + Nn;        // 2        -- zeroed region end
    int* off_e  = cursors + 2;        // E
    int* off_n  = off_e + En;         // N
    int* memb_e = off_n + Nn;         // NNZ
    int* memb_n = memb_e + NNZn;      // NNZ
    float* outp = (float*)d_out;

    // 0. zero counters/cursors (async memset is graph-capture safe)
    hipMemsetAsync(cnt_e, 0, (size_t)(2 * (En + Nn) + 2) * sizeof(int), stream);
    // 1. fused prologue: wprod | img gather | W2t | text gather | W1t | PE | count
    prep_all<<<SEG_END, 256, 0, stream>>>(pe_tab, W1, W1t, W2, W2t, Wt, bt, Wi, bi,
                                          W12t, bias12, bias2w, node_idx, edge_idx,
                                          cnt_e, cnt_n, text_table, img_table, rel,
                                          Atx, Aim);
    // 2-3. CSR build (unordered buckets; no scan)
    offs_kernel<<<(Nn + 255) / 256, 256, 0, stream>>>(cnt_e, cnt_n, off_e, off_n, invE, invN, cursors);
    fill_csr<<<(NNZn + 255) / 256, 256, 0, stream>>>(node_idx, edge_idx, off_e, off_n,
                                                     cur_e, cur_n, memb_e, memb_n, NNZn);
    // 4. projections from packed A (img tiles first for LPT) -> packed bf16 xg
    dim3 grdP(1, 300, 1);
    gemm_proj<<<grdP, 256, 0, stream>>>(Atx, Aim, W1t, W2t, b1, b2, pe_tab, xg);
    // 5-6. first aggregation round: zg = A xg
    agg_kernel<<<En / 4, 256, 0, stream>>>(xg, eP, memb_e, off_e, cnt_e, invE, En);
    agg_kernel<<<Nn / 4, 256, 0, stream>>>(eP, zg, memb_n, off_n, cnt_n, invN, Nn);
    // 7. fused tail: per-b second agg round (rows b*Ln only) + conv + attention chain
    tail_all<<<Bn, 384, 0, stream>>>(zg, W12t, bias12, bias2w, off_e, cnt_e, memb_e,
                                     off_n, cnt_n, memb_n, invE, invN, user_table, uid,
                                     W3, b3, Wq, Wk, Wv, Wo, Wd, bd, W4, b4, outp);
}